// Round 8
// baseline (706.963 us; speedup 1.0000x reference)
//
#include <hip/hip_runtime.h>
#include <hip/hip_bf16.h>
#include <math.h>

#define Bc 2
#define Lc 1024
#define Dc 768
#define Hc 12
#define DHc 64
#define BLD (Bc * Lc * Dc)   // 1,572,864
#define Mrows (Bc * Lc)      // 2048
#define CS 64
#define NC (Lc / CS)         // 16
#define STATE (DHc * DHc + DHc)  // 4160

using f32x4  = __attribute__((ext_vector_type(4))) float;
using bf16x8 = __attribute__((ext_vector_type(8))) short;

__device__ inline short f2bf(float x) {  // RNE fp32 -> bf16 bits
    unsigned u = __builtin_bit_cast(unsigned, x);
    u = (u + 0x7FFFu + ((u >> 16) & 1u)) >> 16;
    return (short)u;
}
__device__ inline float bf2f(short s) {
    unsigned u = ((unsigned)(unsigned short)s) << 16;
    return __builtin_bit_cast(float, u);
}

// ---------------------------------------------------------------------------
// LayerNorm + emit bf16 hi/lo splits of BOTH raw x and normalized xn
// ---------------------------------------------------------------------------
__global__ __launch_bounds__(256) void ln_kernel(const float* __restrict__ x,
                                                 const float* __restrict__ g,
                                                 const float* __restrict__ b,
                                                 short* __restrict__ xh,
                                                 short* __restrict__ xl,
                                                 short* __restrict__ xnh,
                                                 short* __restrict__ xnl) {
    const int row = blockIdx.x;
    const float* xr = x + (size_t)row * Dc;
    float v[3];
    float s = 0.f, ss = 0.f;
#pragma unroll
    for (int i = 0; i < 3; ++i) {
        v[i] = xr[threadIdx.x + i * 256];
        s += v[i];
        ss += v[i] * v[i];
    }
#pragma unroll
    for (int off = 32; off > 0; off >>= 1) {
        s  += __shfl_down(s, off, 64);
        ss += __shfl_down(ss, off, 64);
    }
    __shared__ float sw[2][4];
    const int wave = threadIdx.x >> 6;
    const int lane = threadIdx.x & 63;
    if (lane == 0) { sw[0][wave] = s; sw[1][wave] = ss; }
    __syncthreads();
    s  = sw[0][0] + sw[0][1] + sw[0][2] + sw[0][3];
    ss = sw[1][0] + sw[1][1] + sw[1][2] + sw[1][3];
    const float mu = s * (1.f / Dc);
    const float var = ss * (1.f / Dc) - mu * mu;
    const float rstd = rsqrtf(var + 1e-5f);
    const size_t base = (size_t)row * Dc;
#pragma unroll
    for (int i = 0; i < 3; ++i) {
        const int c = threadIdx.x + i * 256;
        const float xv = v[i];
        short hh = f2bf(xv);
        xh[base + c] = hh;
        xl[base + c] = f2bf(xv - bf2f(hh));
        const float xnv = (xv - mu) * rstd * g[c] + b[c];
        hh = f2bf(xnv);
        xnh[base + c] = hh;
        xnl[base + c] = f2bf(xnv - bf2f(hh));
    }
}

// ---------------------------------------------------------------------------
// Merged weight transpose + split for all three weights (one launch).
// W (K x N) fp32 -> Wh, Wl (N x K) bf16. 32x32 tiles.
// blocks: [0,576) gate, [576,2304) qkv, [2304,2880) proj
// ---------------------------------------------------------------------------
__device__ __forceinline__ void tsp_tile(const float* __restrict__ W,
                                         short* __restrict__ Wh,
                                         short* __restrict__ Wl,
                                         int N, int bx, int by, int tid) {
    __shared__ float t[32][33];
    const int tx = tid & 31, ty = tid >> 5;  // ty 0..7
#pragma unroll
    for (int j = 0; j < 4; ++j)
        t[ty + 8 * j][tx] = W[(size_t)(by * 32 + ty + 8 * j) * N + bx * 32 + tx];
    __syncthreads();
#pragma unroll
    for (int j = 0; j < 4; ++j) {
        const float v = t[tx][ty + 8 * j];
        const short hh = f2bf(v);
        const size_t o = (size_t)(bx * 32 + ty + 8 * j) * Dc + by * 32 + tx;
        Wh[o] = hh;
        Wl[o] = f2bf(v - bf2f(hh));
    }
}

__global__ __launch_bounds__(256) void transpose_all(const float* __restrict__ Wg,
                                                     const float* __restrict__ Wq,
                                                     const float* __restrict__ Wp,
                                                     short* __restrict__ wgh, short* __restrict__ wgl,
                                                     short* __restrict__ wqh, short* __restrict__ wql,
                                                     short* __restrict__ wph, short* __restrict__ wpl) {
    const int bid = blockIdx.x;
    const int tid = threadIdx.x;
    if (bid < 576) {
        tsp_tile(Wg, wgh, wgl, Dc, bid % 24, bid / 24, tid);
    } else if (bid < 2304) {
        const int b = bid - 576;
        tsp_tile(Wq, wqh, wql, 3 * Dc, b % 72, b / 72, tid);
    } else {
        const int b = bid - 2304;
        tsp_tile(Wp, wph, wpl, Dc, b % 24, b / 24, tid);
    }
}

// ---------------------------------------------------------------------------
// Single-wave MFMA GEMM, virtual K' = 3*768 (hi*hi + lo*hi + hi*lo).
// Block = 1 wave = 64 threads, tile 64x64 as 4x4 of 16x16x32 bf16 MFMA.
// BK=32 -> 72 stages. 3 LDS buffers (24KB), 3 reg sets, 2-stage lookahead,
// NO barriers (single wave). Conflict-free K-major chunk layout:
//   chunk(row,kc) = (row>>3)*32 + kc*8 + ((row&7) ^ (kc<<1))
// EPI: 0 none, 1 sigmoid, 2 qkv featurize.
// ---------------------------------------------------------------------------
template <int EPI>
__global__ __launch_bounds__(64) void gemm_w64(const short* __restrict__ Ah,
                                               const short* __restrict__ Al,
                                               const short* __restrict__ Bh,
                                               const short* __restrict__ Bl,
                                               const float* __restrict__ bias,
                                               const float* __restrict__ gate,
                                               float* __restrict__ C, int N) {
    __shared__ float4 lds[3][2][256];  // [buf][A|B][4KB]
    const int l = threadIdx.x;
    const int row0 = blockIdx.y * 64;
    const int col0 = blockIdx.x * 64;

    // frag-read byte offsets: fi -> row = fi*16+(l&15), kc = l>>4
    int rd[4];
#pragma unroll
    for (int fi = 0; fi < 4; ++fi) {
        const int row = fi * 16 + (l & 15);
        const int kc = l >> 4;
        rd[fi] = 16 * (((row >> 3) * 32) + kc * 8 + ((row & 7) ^ (kc << 1)));
    }
    // stage-write byte offsets + global element offsets: j -> row = j*16+(l>>2), kc = l&3
    int wr4[4], ga[4], gb[4];
#pragma unroll
    for (int j = 0; j < 4; ++j) {
        const int row = j * 16 + (l >> 2);
        const int kc = l & 3;
        wr4[j] = 16 * (((row >> 3) * 32) + kc * 8 + ((row & 7) ^ (kc << 1)));
        ga[j] = (row0 + row) * Dc + kc * 8;
        gb[j] = (col0 + row) * Dc + kc * 8;
    }

    f32x4 acc[4][4];
    const f32x4 zero = {0.f, 0.f, 0.f, 0.f};
#pragma unroll
    for (int i = 0; i < 4; ++i)
#pragma unroll
        for (int j = 0; j < 4; ++j) acc[i][j] = zero;

    float4 sa0[4], sb0[4], sa1[4], sb1[4], sa2[4], sb2[4];

#define GLOAD(da, db, sidx)                                                  \
    {                                                                        \
        const int s_ = (sidx);                                               \
        const int seg_ = s_ / 24;                                            \
        const int k0_ = (s_ - seg_ * 24) * 32;                               \
        const short* pa_ = (seg_ == 1 ? Al : Ah) + k0_;                      \
        const short* pb_ = (seg_ == 2 ? Bl : Bh) + k0_;                      \
        _Pragma("unroll") for (int j = 0; j < 4; ++j) {                      \
            da[j] = *reinterpret_cast<const float4*>(pa_ + ga[j]);           \
            db[j] = *reinterpret_cast<const float4*>(pb_ + gb[j]);           \
        }                                                                    \
    }

#define DSWR(bufi, da, db)                                                   \
    {                                                                        \
        char* base_ = (char*)&lds[bufi][0][0];                               \
        _Pragma("unroll") for (int j = 0; j < 4; ++j) {                      \
            *reinterpret_cast<float4*>(base_ + wr4[j]) = da[j];              \
            *reinterpret_cast<float4*>(base_ + 4096 + wr4[j]) = db[j];       \
        }                                                                    \
    }

#define COMPUTE(bufi)                                                        \
    {                                                                        \
        const char* base_ = (const char*)&lds[bufi][0][0];                   \
        bf16x8 fa[4], fb[4];                                                 \
        _Pragma("unroll") for (int f = 0; f < 4; ++f) {                      \
            fa[f] = *reinterpret_cast<const bf16x8*>(base_ + rd[f]);         \
            fb[f] = *reinterpret_cast<const bf16x8*>(base_ + 4096 + rd[f]);  \
        }                                                                    \
        _Pragma("unroll") for (int fi = 0; fi < 4; ++fi)                     \
            _Pragma("unroll") for (int fj = 0; fj < 4; ++fj)                 \
                acc[fi][fj] = __builtin_amdgcn_mfma_f32_16x16x32_bf16(       \
                    fa[fi], fb[fj], acc[fi][fj], 0, 0, 0);                   \
    }

    // Prologue: stage x lives in reg set x%3; buf0 pre-written
    GLOAD(sa0, sb0, 0);
    GLOAD(sa1, sb1, 1);
    DSWR(0, sa0, sb0);
    GLOAD(sa2, sb2, 2);

    for (int it = 0; it < 23; ++it) {
        const int s = it * 3;
        GLOAD(sa0, sb0, s + 3);
        DSWR(1, sa1, sb1);
        COMPUTE(0);
        GLOAD(sa1, sb1, s + 4);
        DSWR(2, sa2, sb2);
        COMPUTE(1);
        GLOAD(sa2, sb2, s + 5);
        DSWR(0, sa0, sb0);
        COMPUTE(2);
    }
    // Epilogue stages 69,70,71
    DSWR(1, sa1, sb1);
    COMPUTE(0);
    DSWR(2, sa2, sb2);
    COMPUTE(1);
    COMPUTE(2);

#undef GLOAD
#undef DSWR
#undef COMPUTE

    // C/D mapping (verified): col = lane&15, row = (lane>>4)*4 + reg
    const int l15 = l & 15;
    const int l4 = l >> 4;
#pragma unroll
    for (int fi = 0; fi < 4; ++fi) {
#pragma unroll
        for (int fj = 0; fj < 4; ++fj) {
            const int col = col0 + fj * 16 + l15;
            const int rowb = row0 + fi * 16 + l4 * 4;
            const float bv = bias[col];
#pragma unroll
            for (int j = 0; j < 4; ++j) {
                float v = acc[fi][fj][j] + bv;
                const int r = rowb + j;
                if (EPI == 1) v = 1.f / (1.f + expf(-v));
                if (EPI == 2) {
                    if (col < 2 * Dc) {
                        float t = v;
                        if (col >= Dc) t *= gate[(size_t)r * Dc + (col - Dc)];
                        v = t > 0.f ? t + 1.f : expf(t);
                    }
                }
                C[(size_t)r * N + col] = v;
            }
        }
    }
}

// ---------------------------------------------------------------------------
// Phase A: chunk-local KV state = K_c^T @ V_c (64x64) and ksum (unchanged)
// ---------------------------------------------------------------------------
__global__ __launch_bounds__(256) void chunk_kv(const float* __restrict__ qkv,
                                                float* __restrict__ cbuf) {
    const int c = blockIdx.x, bh = blockIdx.y;
    const int b = bh / Hc, h = bh % Hc;
    const int tid = threadIdx.x;
    const int e  = tid & 63;
    const int g4 = tid >> 6;
    const int d0 = g4 * 16;

    __shared__ float Ks[CS][DHc];

    const size_t row0  = (size_t)b * Lc + c * CS;
    const size_t qbase = row0 * (3 * Dc) + h * DHc;
#pragma unroll
    for (int j = 0; j < 4; ++j) {
        const int fi = tid + j * 256;
        const int r  = fi >> 4;
        const int c4 = (fi & 15) * 4;
        *reinterpret_cast<float4*>(&Ks[r][c4]) =
            *reinterpret_cast<const float4*>(&qkv[qbase + (size_t)r * 3 * Dc + Dc + c4]);
    }
    __syncthreads();

    float S[16];
#pragma unroll
    for (int i = 0; i < 16; ++i) S[i] = 0.f;
    float ksum = 0.f;
    for (int lq = 0; lq < CS; ++lq) {
        const float vv = qkv[qbase + (size_t)lq * 3 * Dc + 2 * Dc + e];
        if (g4 == 0) ksum += Ks[lq][e];
#pragma unroll
        for (int i4 = 0; i4 < 4; ++i4) {
            const float4 k4 = *reinterpret_cast<const float4*>(&Ks[lq][d0 + i4 * 4]);
            S[i4 * 4 + 0] = fmaf(k4.x, vv, S[i4 * 4 + 0]);
            S[i4 * 4 + 1] = fmaf(k4.y, vv, S[i4 * 4 + 1]);
            S[i4 * 4 + 2] = fmaf(k4.z, vv, S[i4 * 4 + 2]);
            S[i4 * 4 + 3] = fmaf(k4.w, vv, S[i4 * 4 + 3]);
        }
    }
    float* out = cbuf + ((size_t)bh * NC + c) * STATE;
#pragma unroll
    for (int i = 0; i < 16; ++i) out[(d0 + i) * DHc + e] = S[i];
    if (g4 == 0) out[DHc * DHc + e] = ksum;
}

// ---------------------------------------------------------------------------
// Phase B: exclusive prefix scan over NC chunk states (unchanged)
// ---------------------------------------------------------------------------
__global__ __launch_bounds__(256) void scan_kernel(float* __restrict__ cbuf) {
    const int idx = blockIdx.x * 256 + threadIdx.x;
    if (idx >= STATE) return;
    float* base = cbuf + (size_t)blockIdx.y * NC * STATE + idx;
    float r = 0.f;
    for (int c = 0; c < NC; ++c) {
        const float cur = base[(size_t)c * STATE];
        base[(size_t)c * STATE] = r;
        r += cur;
    }
}

// ---------------------------------------------------------------------------
// Phase C (matrix form) -> writes attn as bf16 hi/lo splits (unchanged)
// ---------------------------------------------------------------------------
__global__ __launch_bounds__(256) void chunk_qkv_out(const float* __restrict__ qkv,
                                                     const float* __restrict__ cbuf,
                                                     short* __restrict__ attnh,
                                                     short* __restrict__ attnl) {
    const int c = blockIdx.x, bh = blockIdx.y;
    const int b = bh / Hc, h = bh % Hc;
    const int tid = threadIdx.x;
    const int e  = tid & 63;
    const int g4 = tid >> 6;
    const int l0 = g4 * 16;

    __shared__ float Qs[64][68];
    __shared__ float Kt[64][65];
    __shared__ float Ss[64][68];
    __shared__ float dq[64];

    const size_t row0  = (size_t)b * Lc + c * CS;
    const size_t qbase = row0 * (3 * Dc) + h * DHc;

#pragma unroll
    for (int j = 0; j < 4; ++j) {
        const int fi = tid + j * 256;
        const int r  = fi >> 4;
        const int c4 = (fi & 15) * 4;
        const float4 q4 = *reinterpret_cast<const float4*>(
            &qkv[qbase + (size_t)r * 3 * Dc + c4]);
        *reinterpret_cast<float4*>(&Qs[r][c4]) = q4;
        const float4 k4 = *reinterpret_cast<const float4*>(
            &qkv[qbase + (size_t)r * 3 * Dc + Dc + c4]);
        Kt[c4 + 0][r] = k4.x;
        Kt[c4 + 1][r] = k4.y;
        Kt[c4 + 2][r] = k4.z;
        Kt[c4 + 3][r] = k4.w;
    }
    __syncthreads();

    const float* Pp  = cbuf + ((size_t)bh * NC + c) * STATE;
    const float* kcP = Pp + DHc * DHc;

    float acc[16];
#pragma unroll
    for (int i = 0; i < 16; ++i) acc[i] = 0.f;
#pragma unroll 4
    for (int d4 = 0; d4 < 16; ++d4) {
        const float k0 = Kt[d4 * 4 + 0][e];
        const float k1 = Kt[d4 * 4 + 1][e];
        const float k2 = Kt[d4 * 4 + 2][e];
        const float k3 = Kt[d4 * 4 + 3][e];
#pragma unroll
        for (int i = 0; i < 16; ++i) {
            const float4 q4 = *reinterpret_cast<const float4*>(&Qs[l0 + i][d4 * 4]);
            acc[i] = fmaf(q4.x, k0, acc[i]);
            acc[i] = fmaf(q4.y, k1, acc[i]);
            acc[i] = fmaf(q4.z, k2, acc[i]);
            acc[i] = fmaf(q4.w, k3, acc[i]);
        }
    }
    float den[16];
#pragma unroll
    for (int i = 0; i < 16; ++i) {
        const float m = (e <= l0 + i) ? acc[i] : 0.f;
        Ss[l0 + i][e] = m;
        float r = m;
#pragma unroll
        for (int off = 32; off > 0; off >>= 1) r += __shfl_xor(r, off, 64);
        den[i] = r;
    }
    if (g4 == 0) {
        float s = 0.f;
#pragma unroll 8
        for (int d = 0; d < 64; ++d) s = fmaf(Qs[e][d], kcP[d], s);
        dq[e] = s;
    }
    __syncthreads();

    float num[16];
#pragma unroll
    for (int i = 0; i < 16; ++i) num[i] = 0.f;
#pragma unroll 4
    for (int d4 = 0; d4 < 16; ++d4) {
        const float p0 = Pp[(d4 * 4 + 0) * DHc + e];
        const float p1 = Pp[(d4 * 4 + 1) * DHc + e];
        const float p2 = Pp[(d4 * 4 + 2) * DHc + e];
        const float p3 = Pp[(d4 * 4 + 3) * DHc + e];
#pragma unroll
        for (int i = 0; i < 16; ++i) {
            const float4 q4 = *reinterpret_cast<const float4*>(&Qs[l0 + i][d4 * 4]);
            num[i] = fmaf(q4.x, p0, num[i]);
            num[i] = fmaf(q4.y, p1, num[i]);
            num[i] = fmaf(q4.z, p2, num[i]);
            num[i] = fmaf(q4.w, p3, num[i]);
        }
    }
#pragma unroll 4
    for (int j4 = 0; j4 < 16; ++j4) {
        const float v0 = qkv[qbase + (size_t)(j4 * 4 + 0) * 3 * Dc + 2 * Dc + e];
        const float v1 = qkv[qbase + (size_t)(j4 * 4 + 1) * 3 * Dc + 2 * Dc + e];
        const float v2 = qkv[qbase + (size_t)(j4 * 4 + 2) * 3 * Dc + 2 * Dc + e];
        const float v3 = qkv[qbase + (size_t)(j4 * 4 + 3) * 3 * Dc + 2 * Dc + e];
#pragma unroll
        for (int i = 0; i < 16; ++i) {
            const float4 s4 = *reinterpret_cast<const float4*>(&Ss[l0 + i][j4 * 4]);
            num[i] = fmaf(s4.x, v0, num[i]);
            num[i] = fmaf(s4.y, v1, num[i]);
            num[i] = fmaf(s4.z, v2, num[i]);
            num[i] = fmaf(s4.w, v3, num[i]);
        }
    }
#pragma unroll
    for (int i = 0; i < 16; ++i) {
        const float dd = den[i] + dq[l0 + i] + 1e-6f;
        const float o = num[i] / dd;
        const size_t oidx = (row0 + l0 + i) * Dc + h * DHc + e;
        const short hh = f2bf(o);
        attnh[oidx] = hh;
        attnl[oidx] = f2bf(o - bf2f(hh));
    }
}

// ---------------------------------------------------------------------------
extern "C" void kernel_launch(void* const* d_in, const int* in_sizes, int n_in,
                              void* d_out, int out_size, void* d_ws, size_t ws_size,
                              hipStream_t stream) {
    const float* x      = (const float*)d_in[0];
    const float* W_qkv  = (const float*)d_in[1];
    const float* b_qkv  = (const float*)d_in[2];
    const float* W_gate = (const float*)d_in[3];
    const float* b_gate = (const float*)d_in[4];
    const float* W_proj = (const float*)d_in[5];
    const float* b_proj = (const float*)d_in[6];
    const float* ln_g   = (const float*)d_in[7];
    const float* ln_b   = (const float*)d_in[8];

    float* out_proj = (float*)d_out;           // (B,L,D)
    float* out_gate = out_proj + (size_t)BLD;  // (B,L,D)

    float* ws  = (float*)d_ws;
    float* qkv = ws;                                  // 3*BLD fp32 (featurized)
    short* S   = (short*)(ws + (size_t)3 * BLD);
    short* xnh = S;
    short* xnl = xnh + (size_t)BLD;
    short* xh  = xnl + (size_t)BLD;
    short* xl  = xh  + (size_t)BLD;
    float* cbuf = (float*)xnh;                        // alias: x/xn splits dead after gemms
    short* wqh = xl + (size_t)BLD;                    // 2304*768 shorts
    short* wql = wqh + (size_t)3 * Dc * Dc;
    short* attnh = wqh;                               // alias: wq dead after qkv gemm
    short* attnl = attnh + (size_t)BLD;
    short* wgh = wql + (size_t)3 * Dc * Dc;           // 768*768 shorts each
    short* wgl = wgh + (size_t)Dc * Dc;
    short* wph = wgl + (size_t)Dc * Dc;
    short* wpl = wph + (size_t)Dc * Dc;

    // 1) weight transposes + splits (one launch)
    transpose_all<<<2880, 256, 0, stream>>>(W_gate, W_qkv, W_proj,
                                            wgh, wgl, wqh, wql, wph, wpl);
    // 2) LayerNorm + x/xn bf16 splits
    ln_kernel<<<Mrows, 256, 0, stream>>>(x, ln_g, ln_b, xh, xl, xnh, xnl);
    // 3) gate = sigmoid(x @ W_gate + b_gate)
    gemm_w64<1><<<dim3(Dc / 64, Mrows / 64), 64, 0, stream>>>(
        xh, xl, wgh, wgl, b_gate, nullptr, out_gate, Dc);
    // 4) qkv = xn @ W_qkv + b_qkv, featurized epilogue
    gemm_w64<2><<<dim3(3 * Dc / 64, Mrows / 64), 64, 0, stream>>>(
        xnh, xnl, wqh, wql, b_qkv, out_gate, qkv, 3 * Dc);
    // 5-7) chunked causal linear attention
    chunk_kv<<<dim3(NC, Bc * Hc), 256, 0, stream>>>(qkv, cbuf);
    scan_kernel<<<dim3(17, Bc * Hc), 256, 0, stream>>>(cbuf);
    chunk_qkv_out<<<dim3(NC, Bc * Hc), 256, 0, stream>>>(qkv, cbuf, attnh, attnl);
    // 8) out = attn @ W_proj + b_proj
    gemm_w64<0><<<dim3(Dc / 64, Mrows / 64), 64, 0, stream>>>(
        attnh, attnl, wph, wpl, b_proj, nullptr, out_proj, Dc);
}

// Round 9
// 261.520 us; speedup vs baseline: 2.7033x; 2.7033x over previous
//
#include <hip/hip_runtime.h>
#include <hip/hip_bf16.h>
#include <math.h>

#define Bc 2
#define Lc 1024
#define Dc 768
#define Hc 12
#define DHc 64
#define BLD (Bc * Lc * Dc)   // 1,572,864
#define Mrows (Bc * Lc)      // 2048
#define CS 64
#define NC (Lc / CS)         // 16
#define STATE (DHc * DHc + DHc)  // 4160

using f32x4  = __attribute__((ext_vector_type(4))) float;
using bf16x8 = __attribute__((ext_vector_type(8))) short;
typedef unsigned int u32;

__device__ inline short f2bf(float x) {  // RNE fp32 -> bf16 bits
    unsigned u = __builtin_bit_cast(unsigned, x);
    u = (u + 0x7FFFu + ((u >> 16) & 1u)) >> 16;
    return (short)u;
}
__device__ inline float bf2f(short s) {
    unsigned u = ((unsigned)(unsigned short)s) << 16;
    return __builtin_bit_cast(float, u);
}
__device__ __forceinline__ void gll16(const short* g, short* l) {
    __builtin_amdgcn_global_load_lds(
        (const __attribute__((address_space(1))) u32*)g,
        (__attribute__((address_space(3))) u32*)l, 16, 0, 0);
}

// ---------------------------------------------------------------------------
// LayerNorm + emit bf16 hi/lo splits of BOTH raw x and normalized xn
// ---------------------------------------------------------------------------
__global__ __launch_bounds__(256) void ln_kernel(const float* __restrict__ x,
                                                 const float* __restrict__ g,
                                                 const float* __restrict__ b,
                                                 short* __restrict__ xh,
                                                 short* __restrict__ xl,
                                                 short* __restrict__ xnh,
                                                 short* __restrict__ xnl) {
    const int row = blockIdx.x;
    const float* xr = x + (size_t)row * Dc;
    float v[3];
    float s = 0.f, ss = 0.f;
#pragma unroll
    for (int i = 0; i < 3; ++i) {
        v[i] = xr[threadIdx.x + i * 256];
        s += v[i];
        ss += v[i] * v[i];
    }
#pragma unroll
    for (int off = 32; off > 0; off >>= 1) {
        s  += __shfl_down(s, off, 64);
        ss += __shfl_down(ss, off, 64);
    }
    __shared__ float sw[2][4];
    const int wave = threadIdx.x >> 6;
    const int lane = threadIdx.x & 63;
    if (lane == 0) { sw[0][wave] = s; sw[1][wave] = ss; }
    __syncthreads();
    s  = sw[0][0] + sw[0][1] + sw[0][2] + sw[0][3];
    ss = sw[1][0] + sw[1][1] + sw[1][2] + sw[1][3];
    const float mu = s * (1.f / Dc);
    const float var = ss * (1.f / Dc) - mu * mu;
    const float rstd = rsqrtf(var + 1e-5f);
    const size_t base = (size_t)row * Dc;
#pragma unroll
    for (int i = 0; i < 3; ++i) {
        const int c = threadIdx.x + i * 256;
        const float xv = v[i];
        short hh = f2bf(xv);
        xh[base + c] = hh;
        xl[base + c] = f2bf(xv - bf2f(hh));
        const float xnv = (xv - mu) * rstd * g[c] + b[c];
        hh = f2bf(xnv);
        xnh[base + c] = hh;
        xnl[base + c] = f2bf(xnv - bf2f(hh));
    }
}

// ---------------------------------------------------------------------------
// Merged weight transpose + split (one launch). W (K x N) fp32 -> (N x K) bf16
// ---------------------------------------------------------------------------
__device__ __forceinline__ void tsp_tile(const float* __restrict__ W,
                                         short* __restrict__ Wh,
                                         short* __restrict__ Wl,
                                         int N, int bx, int by, int tid) {
    __shared__ float t[32][33];
    const int tx = tid & 31, ty = tid >> 5;  // ty 0..7
#pragma unroll
    for (int j = 0; j < 4; ++j)
        t[ty + 8 * j][tx] = W[(size_t)(by * 32 + ty + 8 * j) * N + bx * 32 + tx];
    __syncthreads();
#pragma unroll
    for (int j = 0; j < 4; ++j) {
        const float v = t[tx][ty + 8 * j];
        const short hh = f2bf(v);
        const size_t o = (size_t)(bx * 32 + ty + 8 * j) * Dc + by * 32 + tx;
        Wh[o] = hh;
        Wl[o] = f2bf(v - bf2f(hh));
    }
}

__global__ __launch_bounds__(256) void transpose_all(const float* __restrict__ Wg,
                                                     const float* __restrict__ Wq,
                                                     const float* __restrict__ Wp,
                                                     short* __restrict__ wgh, short* __restrict__ wgl,
                                                     short* __restrict__ wqh, short* __restrict__ wql,
                                                     short* __restrict__ wph, short* __restrict__ wpl) {
    const int bid = blockIdx.x;
    const int tid = threadIdx.x;
    if (bid < 576) {
        tsp_tile(Wg, wgh, wgl, Dc, bid % 24, bid / 24, tid);
    } else if (bid < 2304) {
        const int b = bid - 576;
        tsp_tile(Wq, wqh, wql, 3 * Dc, b % 72, b / 72, tid);
    } else {
        const int b = bid - 2304;
        tsp_tile(Wp, wph, wpl, Dc, b % 24, b / 24, tid);
    }
}

// ---------------------------------------------------------------------------
// Wave-split-K MFMA GEMM, virtual K' = 3*768 (hi*hi + lo*hi + hi*lo).
// 4 waves/block; EACH wave computes the full 64x64 tile over K'/4 = 576
// (18 stages of BK=32), then a cross-wave LDS reduction sums the 4 partials.
// Staging: global_load_lds into wave-PRIVATE double-buffered 16KB slab;
// NO block barriers in the K-loop; counted vmcnt(8) = 2-stage prefetch depth;
// lgkmcnt(0) before re-staging a buffer (DMA vs ds_read ordering).
// LDS chunk layout: phys_chunk = k_chunk ^ ((row>>1)&3)  (uniform 2-way, free).
// EPI: 0 none, 1 sigmoid, 2 qkv featurize.
// ---------------------------------------------------------------------------
template <int EPI>
__global__ __launch_bounds__(256) void gemm_ws(const short* __restrict__ Ah,
                                               const short* __restrict__ Al,
                                               const short* __restrict__ Bh,
                                               const short* __restrict__ Bl,
                                               const float* __restrict__ bias,
                                               const float* __restrict__ gate,
                                               float* __restrict__ C, int N) {
    __shared__ __align__(16) char smem[65536];  // 4 waves x [2 buf][A|B][4KB]; aliased by reduce
    const int tid = threadIdx.x;
    const int l = tid & 63;
    const int w = tid >> 6;
    const int row0 = blockIdx.y * 64;
    const int col0 = blockIdx.x * 64;

    // per-lane pre-swizzled global element offsets (gll16 j covers rows j*16..+15)
    const int swz = 8 * ((l & 3) ^ ((l >> 3) & 3));
    int gao[4], gbo[4];
#pragma unroll
    for (int j = 0; j < 4; ++j) {
        gao[j] = (row0 + j * 16 + (l >> 2)) * Dc + swz;
        gbo[j] = (col0 + j * 16 + (l >> 2)) * Dc + swz;
    }
    // frag-read byte offset: row=l&15 (+fi*16 via +fi*1024), phys chunk swizzled
    const int r15 = l & 15;
    const int rdo = 16 * (4 * r15 + ((l >> 4) ^ ((r15 >> 1) & 3)));

    f32x4 acc[4][4];
    const f32x4 zero = {0.f, 0.f, 0.f, 0.f};
#pragma unroll
    for (int i = 0; i < 4; ++i)
#pragma unroll
        for (int j = 0; j < 4; ++j) acc[i][j] = zero;

    char* slab = smem + w * 16384;  // [buf][A 4KB | B 4KB]

    auto STAGE = [&](int b, int s) {  // s = global stage 0..71
        const int seg = s / 24;
        const int kk = (s - seg * 24) * 32;
        const short* pa = (seg == 1 ? Al : Ah) + kk;
        const short* pb = (seg == 2 ? Bl : Bh) + kk;
        short* da = (short*)(slab + b * 8192);
        short* db = (short*)(slab + b * 8192 + 4096);
#pragma unroll
        for (int j = 0; j < 4; ++j) {
            gll16(pa + gao[j], da + j * 512);
            gll16(pb + gbo[j], db + j * 512);
        }
    };

    const int s0 = w * 18;
    STAGE(0, s0);
    STAGE(1, s0 + 1);

    for (int i = 0; i < 18; ++i) {
        if (i < 17) asm volatile("s_waitcnt vmcnt(8)" ::: "memory");
        else        asm volatile("s_waitcnt vmcnt(0)" ::: "memory");
        // compute stage i from buf i&1
        {
            const char* ba = slab + (i & 1) * 8192;
            const char* bb = ba + 4096;
            bf16x8 fa[4], fb[4];
#pragma unroll
            for (int f = 0; f < 4; ++f) {
                fa[f] = *reinterpret_cast<const bf16x8*>(ba + f * 1024 + rdo);
                fb[f] = *reinterpret_cast<const bf16x8*>(bb + f * 1024 + rdo);
            }
#pragma unroll
            for (int fi = 0; fi < 4; ++fi)
#pragma unroll
                for (int fj = 0; fj < 4; ++fj)
                    acc[fi][fj] = __builtin_amdgcn_mfma_f32_16x16x32_bf16(
                        fa[fi], fb[fj], acc[fi][fj], 0, 0, 0);
        }
        // ds_reads of this buffer must retire before DMA overwrites it
        asm volatile("s_waitcnt lgkmcnt(0)" ::: "memory");
        if (i + 2 < 18) STAGE(i & 1, s0 + i + 2);
    }

    // ---- cross-wave reduction (aliases staging LDS) ----
    __syncthreads();
    float* red = (float*)smem;  // [4][64][64]
    const int l4 = l >> 4;
#pragma unroll
    for (int fi = 0; fi < 4; ++fi)
#pragma unroll
        for (int fj = 0; fj < 4; ++fj)
#pragma unroll
            for (int j = 0; j < 4; ++j)
                red[(w * 64 + fi * 16 + l4 * 4 + j) * 64 + fj * 16 + (l & 15)] =
                    acc[fi][fj][j];
    __syncthreads();

    const int rr = tid >> 2;           // 0..63 row
    const int cc0 = (tid & 3) * 16;    // col base
    const size_t grow = (size_t)(row0 + rr);
#pragma unroll
    for (int i = 0; i < 16; ++i) {
        const int c = cc0 + i;
        float v = red[rr * 64 + c] + red[(64 + rr) * 64 + c] +
                  red[(128 + rr) * 64 + c] + red[(192 + rr) * 64 + c] +
                  bias[col0 + c];
        const int col = col0 + c;
        if (EPI == 1) v = 1.f / (1.f + expf(-v));
        if (EPI == 2) {
            if (col < 2 * Dc) {
                float t = v;
                if (col >= Dc) t *= gate[grow * Dc + (col - Dc)];
                v = t > 0.f ? t + 1.f : expf(t);
            }
        }
        C[grow * N + col] = v;
    }
}

// ---------------------------------------------------------------------------
// Phase A: chunk-local KV state = K_c^T @ V_c (64x64) and ksum (unchanged)
// ---------------------------------------------------------------------------
__global__ __launch_bounds__(256) void chunk_kv(const float* __restrict__ qkv,
                                                float* __restrict__ cbuf) {
    const int c = blockIdx.x, bh = blockIdx.y;
    const int b = bh / Hc, h = bh % Hc;
    const int tid = threadIdx.x;
    const int e  = tid & 63;
    const int g4 = tid >> 6;
    const int d0 = g4 * 16;

    __shared__ float Ks[CS][DHc];

    const size_t row0  = (size_t)b * Lc + c * CS;
    const size_t qbase = row0 * (3 * Dc) + h * DHc;
#pragma unroll
    for (int j = 0; j < 4; ++j) {
        const int fi = tid + j * 256;
        const int r  = fi >> 4;
        const int c4 = (fi & 15) * 4;
        *reinterpret_cast<float4*>(&Ks[r][c4]) =
            *reinterpret_cast<const float4*>(&qkv[qbase + (size_t)r * 3 * Dc + Dc + c4]);
    }
    __syncthreads();

    float S[16];
#pragma unroll
    for (int i = 0; i < 16; ++i) S[i] = 0.f;
    float ksum = 0.f;
    for (int lq = 0; lq < CS; ++lq) {
        const float vv = qkv[qbase + (size_t)lq * 3 * Dc + 2 * Dc + e];
        if (g4 == 0) ksum += Ks[lq][e];
#pragma unroll
        for (int i4 = 0; i4 < 4; ++i4) {
            const float4 k4 = *reinterpret_cast<const float4*>(&Ks[lq][d0 + i4 * 4]);
            S[i4 * 4 + 0] = fmaf(k4.x, vv, S[i4 * 4 + 0]);
            S[i4 * 4 + 1] = fmaf(k4.y, vv, S[i4 * 4 + 1]);
            S[i4 * 4 + 2] = fmaf(k4.z, vv, S[i4 * 4 + 2]);
            S[i4 * 4 + 3] = fmaf(k4.w, vv, S[i4 * 4 + 3]);
        }
    }
    float* out = cbuf + ((size_t)bh * NC + c) * STATE;
#pragma unroll
    for (int i = 0; i < 16; ++i) out[(d0 + i) * DHc + e] = S[i];
    if (g4 == 0) out[DHc * DHc + e] = ksum;
}

// ---------------------------------------------------------------------------
// Phase B: exclusive prefix scan over NC chunk states (unchanged)
// ---------------------------------------------------------------------------
__global__ __launch_bounds__(256) void scan_kernel(float* __restrict__ cbuf) {
    const int idx = blockIdx.x * 256 + threadIdx.x;
    if (idx >= STATE) return;
    float* base = cbuf + (size_t)blockIdx.y * NC * STATE + idx;
    float r = 0.f;
    for (int c = 0; c < NC; ++c) {
        const float cur = base[(size_t)c * STATE];
        base[(size_t)c * STATE] = r;
        r += cur;
    }
}

// ---------------------------------------------------------------------------
// Phase C (matrix form) -> writes attn as bf16 hi/lo splits (unchanged)
// ---------------------------------------------------------------------------
__global__ __launch_bounds__(256) void chunk_qkv_out(const float* __restrict__ qkv,
                                                     const float* __restrict__ cbuf,
                                                     short* __restrict__ attnh,
                                                     short* __restrict__ attnl) {
    const int c = blockIdx.x, bh = blockIdx.y;
    const int b = bh / Hc, h = bh % Hc;
    const int tid = threadIdx.x;
    const int e  = tid & 63;
    const int g4 = tid >> 6;
    const int l0 = g4 * 16;

    __shared__ float Qs[64][68];
    __shared__ float Kt[64][65];
    __shared__ float Ss[64][68];
    __shared__ float dq[64];

    const size_t row0  = (size_t)b * Lc + c * CS;
    const size_t qbase = row0 * (3 * Dc) + h * DHc;

#pragma unroll
    for (int j = 0; j < 4; ++j) {
        const int fi = tid + j * 256;
        const int r  = fi >> 4;
        const int c4 = (fi & 15) * 4;
        const float4 q4 = *reinterpret_cast<const float4*>(
            &qkv[qbase + (size_t)r * 3 * Dc + c4]);
        *reinterpret_cast<float4*>(&Qs[r][c4]) = q4;
        const float4 k4 = *reinterpret_cast<const float4*>(
            &qkv[qbase + (size_t)r * 3 * Dc + Dc + c4]);
        Kt[c4 + 0][r] = k4.x;
        Kt[c4 + 1][r] = k4.y;
        Kt[c4 + 2][r] = k4.z;
        Kt[c4 + 3][r] = k4.w;
    }
    __syncthreads();

    const float* Pp  = cbuf + ((size_t)bh * NC + c) * STATE;
    const float* kcP = Pp + DHc * DHc;

    float acc[16];
#pragma unroll
    for (int i = 0; i < 16; ++i) acc[i] = 0.f;
#pragma unroll 4
    for (int d4 = 0; d4 < 16; ++d4) {
        const float k0 = Kt[d4 * 4 + 0][e];
        const float k1 = Kt[d4 * 4 + 1][e];
        const float k2 = Kt[d4 * 4 + 2][e];
        const float k3 = Kt[d4 * 4 + 3][e];
#pragma unroll
        for (int i = 0; i < 16; ++i) {
            const float4 q4 = *reinterpret_cast<const float4*>(&Qs[l0 + i][d4 * 4]);
            acc[i] = fmaf(q4.x, k0, acc[i]);
            acc[i] = fmaf(q4.y, k1, acc[i]);
            acc[i] = fmaf(q4.z, k2, acc[i]);
            acc[i] = fmaf(q4.w, k3, acc[i]);
        }
    }
    float den[16];
#pragma unroll
    for (int i = 0; i < 16; ++i) {
        const float m = (e <= l0 + i) ? acc[i] : 0.f;
        Ss[l0 + i][e] = m;
        float r = m;
#pragma unroll
        for (int off = 32; off > 0; off >>= 1) r += __shfl_xor(r, off, 64);
        den[i] = r;
    }
    if (g4 == 0) {
        float s = 0.f;
#pragma unroll 8
        for (int d = 0; d < 64; ++d) s = fmaf(Qs[e][d], kcP[d], s);
        dq[e] = s;
    }
    __syncthreads();

    float num[16];
#pragma unroll
    for (int i = 0; i < 16; ++i) num[i] = 0.f;
#pragma unroll 4
    for (int d4 = 0; d4 < 16; ++d4) {
        const float p0 = Pp[(d4 * 4 + 0) * DHc + e];
        const float p1 = Pp[(d4 * 4 + 1) * DHc + e];
        const float p2 = Pp[(d4 * 4 + 2) * DHc + e];
        const float p3 = Pp[(d4 * 4 + 3) * DHc + e];
#pragma unroll
        for (int i = 0; i < 16; ++i) {
            const float4 q4 = *reinterpret_cast<const float4*>(&Qs[l0 + i][d4 * 4]);
            num[i] = fmaf(q4.x, p0, num[i]);
            num[i] = fmaf(q4.y, p1, num[i]);
            num[i] = fmaf(q4.z, p2, num[i]);
            num[i] = fmaf(q4.w, p3, num[i]);
        }
    }
#pragma unroll 4
    for (int j4 = 0; j4 < 16; ++j4) {
        const float v0 = qkv[qbase + (size_t)(j4 * 4 + 0) * 3 * Dc + 2 * Dc + e];
        const float v1 = qkv[qbase + (size_t)(j4 * 4 + 1) * 3 * Dc + 2 * Dc + e];
        const float v2 = qkv[qbase + (size_t)(j4 * 4 + 2) * 3 * Dc + 2 * Dc + e];
        const float v3 = qkv[qbase + (size_t)(j4 * 4 + 3) * 3 * Dc + 2 * Dc + e];
#pragma unroll
        for (int i = 0; i < 16; ++i) {
            const float4 s4 = *reinterpret_cast<const float4*>(&Ss[l0 + i][j4 * 4]);
            num[i] = fmaf(s4.x, v0, num[i]);
            num[i] = fmaf(s4.y, v1, num[i]);
            num[i] = fmaf(s4.z, v2, num[i]);
            num[i] = fmaf(s4.w, v3, num[i]);
        }
    }
#pragma unroll
    for (int i = 0; i < 16; ++i) {
        const float dd = den[i] + dq[l0 + i] + 1e-6f;
        const float o = num[i] / dd;
        const size_t oidx = (row0 + l0 + i) * Dc + h * DHc + e;
        const short hh = f2bf(o);
        attnh[oidx] = hh;
        attnl[oidx] = f2bf(o - bf2f(hh));
    }
}

// ---------------------------------------------------------------------------
extern "C" void kernel_launch(void* const* d_in, const int* in_sizes, int n_in,
                              void* d_out, int out_size, void* d_ws, size_t ws_size,
                              hipStream_t stream) {
    const float* x      = (const float*)d_in[0];
    const float* W_qkv  = (const float*)d_in[1];
    const float* b_qkv  = (const float*)d_in[2];
    const float* W_gate = (const float*)d_in[3];
    const float* b_gate = (const float*)d_in[4];
    const float* W_proj = (const float*)d_in[5];
    const float* b_proj = (const float*)d_in[6];
    const float* ln_g   = (const float*)d_in[7];
    const float* ln_b   = (const float*)d_in[8];

    float* out_proj = (float*)d_out;           // (B,L,D)
    float* out_gate = out_proj + (size_t)BLD;  // (B,L,D)

    float* ws  = (float*)d_ws;
    float* qkv = ws;                                  // 3*BLD fp32 (featurized)
    short* S   = (short*)(ws + (size_t)3 * BLD);
    short* xnh = S;
    short* xnl = xnh + (size_t)BLD;
    short* xh  = xnl + (size_t)BLD;
    short* xl  = xh  + (size_t)BLD;
    float* cbuf = (float*)xnh;                        // alias: x/xn splits dead after gemms
    short* wqh = xl + (size_t)BLD;                    // 2304*768 shorts
    short* wql = wqh + (size_t)3 * Dc * Dc;
    short* attnh = wqh;                               // alias: wq dead after qkv gemm
    short* attnl = attnh + (size_t)BLD;
    short* wgh = wql + (size_t)3 * Dc * Dc;           // 768*768 shorts each
    short* wgl = wgh + (size_t)Dc * Dc;
    short* wph = wgl + (size_t)Dc * Dc;
    short* wpl = wph + (size_t)Dc * Dc;

    // 1) weight transposes + splits (one launch)
    transpose_all<<<2880, 256, 0, stream>>>(W_gate, W_qkv, W_proj,
                                            wgh, wgl, wqh, wql, wph, wpl);
    // 2) LayerNorm + x/xn bf16 splits
    ln_kernel<<<Mrows, 256, 0, stream>>>(x, ln_g, ln_b, xh, xl, xnh, xnl);
    // 3) gate = sigmoid(x @ W_gate + b_gate)
    gemm_ws<1><<<dim3(Dc / 64, Mrows / 64), 256, 0, stream>>>(
        xh, xl, wgh, wgl, b_gate, nullptr, out_gate, Dc);
    // 4) qkv = xn @ W_qkv + b_qkv, featurized epilogue
    gemm_ws<2><<<dim3(3 * Dc / 64, Mrows / 64), 256, 0, stream>>>(
        xnh, xnl, wqh, wql, b_qkv, out_gate, qkv, 3 * Dc);
    // 5-7) chunked causal linear attention
    chunk_kv<<<dim3(NC, Bc * Hc), 256, 0, stream>>>(qkv, cbuf);
    scan_kernel<<<dim3(17, Bc * Hc), 256, 0, stream>>>(cbuf);
    chunk_qkv_out<<<dim3(NC, Bc * Hc), 256, 0, stream>>>(qkv, cbuf, attnh, attnl);
    // 8) out = attn @ W_proj + b_proj
    gemm_ws<0><<<dim3(Dc / 64, Mrows / 64), 256, 0, stream>>>(
        attnh, attnl, wph, wpl, b_proj, nullptr, out_proj, Dc);
}

// Round 10
// 186.710 us; speedup vs baseline: 3.7864x; 1.4007x over previous
//
#include <hip/hip_runtime.h>
#include <hip/hip_bf16.h>
#include <math.h>

#define Bc 2
#define Lc 1024
#define Dc 768
#define Hc 12
#define DHc 64
#define BLD (Bc * Lc * Dc)   // 1,572,864
#define Mrows (Bc * Lc)      // 2048
#define CS 64
#define NC (Lc / CS)         // 16
#define STATE (DHc * DHc + DHc)  // 4160

using f32x4  = __attribute__((ext_vector_type(4))) float;
using f16x8  = __attribute__((ext_vector_type(8))) _Float16;
typedef unsigned int u32;

__device__ __forceinline__ void gll16(const void* g, void* l) {
    __builtin_amdgcn_global_load_lds(
        (const __attribute__((address_space(1))) u32*)g,
        (__attribute__((address_space(3))) u32*)l, 16, 0, 0);
}

// ---------------------------------------------------------------------------
// LayerNorm + emit f16 copies of raw x and normalized xn
// ---------------------------------------------------------------------------
__global__ __launch_bounds__(256) void ln_kernel(const float* __restrict__ x,
                                                 const float* __restrict__ g,
                                                 const float* __restrict__ b,
                                                 _Float16* __restrict__ xh,
                                                 _Float16* __restrict__ xnh) {
    const int row = blockIdx.x;
    const float* xr = x + (size_t)row * Dc;
    float v[3];
    float s = 0.f, ss = 0.f;
#pragma unroll
    for (int i = 0; i < 3; ++i) {
        v[i] = xr[threadIdx.x + i * 256];
        s += v[i];
        ss += v[i] * v[i];
    }
#pragma unroll
    for (int off = 32; off > 0; off >>= 1) {
        s  += __shfl_down(s, off, 64);
        ss += __shfl_down(ss, off, 64);
    }
    __shared__ float sw[2][4];
    const int wave = threadIdx.x >> 6;
    const int lane = threadIdx.x & 63;
    if (lane == 0) { sw[0][wave] = s; sw[1][wave] = ss; }
    __syncthreads();
    s  = sw[0][0] + sw[0][1] + sw[0][2] + sw[0][3];
    ss = sw[1][0] + sw[1][1] + sw[1][2] + sw[1][3];
    const float mu = s * (1.f / Dc);
    const float var = ss * (1.f / Dc) - mu * mu;
    const float rstd = rsqrtf(var + 1e-5f);
    const size_t base = (size_t)row * Dc;
#pragma unroll
    for (int i = 0; i < 3; ++i) {
        const int c = threadIdx.x + i * 256;
        const float xv = v[i];
        xh[base + c] = (_Float16)xv;
        xnh[base + c] = (_Float16)((xv - mu) * rstd * g[c] + b[c]);
    }
}

// ---------------------------------------------------------------------------
// Merged weight transpose to f16 (one launch). W (K x N) fp32 -> (N x K) f16
// ---------------------------------------------------------------------------
__device__ __forceinline__ void tsp_tile(const float* __restrict__ W,
                                         _Float16* __restrict__ Wh,
                                         int N, int bx, int by, int tid) {
    __shared__ float t[32][33];
    const int tx = tid & 31, ty = tid >> 5;  // ty 0..7
#pragma unroll
    for (int j = 0; j < 4; ++j)
        t[ty + 8 * j][tx] = W[(size_t)(by * 32 + ty + 8 * j) * N + bx * 32 + tx];
    __syncthreads();
#pragma unroll
    for (int j = 0; j < 4; ++j) {
        const size_t o = (size_t)(bx * 32 + ty + 8 * j) * Dc + by * 32 + tx;
        Wh[o] = (_Float16)t[tx][ty + 8 * j];
    }
}

__global__ __launch_bounds__(256) void transpose_all(const float* __restrict__ Wg,
                                                     const float* __restrict__ Wq,
                                                     const float* __restrict__ Wp,
                                                     _Float16* __restrict__ wgh,
                                                     _Float16* __restrict__ wqh,
                                                     _Float16* __restrict__ wph) {
    const int bid = blockIdx.x;
    const int tid = threadIdx.x;
    if (bid < 576) {
        tsp_tile(Wg, wgh, Dc, bid % 24, bid / 24, tid);
    } else if (bid < 2304) {
        const int b = bid - 576;
        tsp_tile(Wq, wqh, 3 * Dc, b % 72, b / 72, tid);
    } else {
        const int b = bid - 2304;
        tsp_tile(Wp, wph, Dc, b % 24, b / 24, tid);
    }
}

// ---------------------------------------------------------------------------
// f16 single-pass MFMA GEMM: C = A @ B^T + bias.  K = 768 -> 12 stages.
// EXACT round-5 structure (measured best: 0 bank conflicts, clean writes):
// 64x64 tile, 4 waves (2x2 of 32x32), BK=64, double-buffered global_load_lds,
// XOR chunk-swizzle (phys = logical ^ (row&7)) on source + ds_read.
// EPI: 0 none, 1 sigmoid, 2 qkv featurize.
// ---------------------------------------------------------------------------
template <int EPI>
__global__ __launch_bounds__(256) void gemm_f16(const _Float16* __restrict__ A,
                                                const _Float16* __restrict__ B,
                                                const float* __restrict__ bias,
                                                const float* __restrict__ gate,
                                                float* __restrict__ C, int N) {
    __shared__ _Float16 Alds[2][64 * 64];
    __shared__ _Float16 Blds[2][64 * 64];
    const int tid  = threadIdx.x;
    const int lane = tid & 63;
    const int wv  = tid >> 6;
    const int wr  = (wv >> 1) * 32;
    const int wc  = (wv & 1) * 32;
    const int l15 = lane & 15;
    const int l4  = lane >> 4;
    const int r8  = lane >> 3;   // 0..7
    const int ch  = lane & 7;    // 0..7
    const int sChunk = ((ch ^ r8) * 8);  // pre-swizzled source element offset
    const int row0 = blockIdx.y * 64;
    const int col0 = blockIdx.x * 64;

    f32x4 acc[2][2];
    const f32x4 zero = {0.f, 0.f, 0.f, 0.f};
#pragma unroll
    for (int i = 0; i < 2; ++i)
#pragma unroll
        for (int j = 0; j < 2; ++j) acc[i][j] = zero;

    auto STAGE = [&](int buf, int s) {
        const _Float16* as = A + (size_t)(row0 + 16 * wv + r8) * 768 + s * 64 + sChunk;
        gll16(as,           &Alds[buf][(16 * wv) * 64]);
        gll16(as + 8 * 768, &Alds[buf][(16 * wv + 8) * 64]);
        const _Float16* bs = B + (size_t)(col0 + 16 * wv + r8) * 768 + s * 64 + sChunk;
        gll16(bs,           &Blds[buf][(16 * wv) * 64]);
        gll16(bs + 8 * 768, &Blds[buf][(16 * wv + 8) * 64]);
    };

    STAGE(0, 0);
    asm volatile("s_waitcnt vmcnt(0)" ::: "memory");
    __builtin_amdgcn_s_barrier();

    const int pa0 = ((l4)     ^ (l15 & 7)) * 8;  // ksub 0 phys chunk
    const int pa1 = ((4 + l4) ^ (l15 & 7)) * 8;  // ksub 1 phys chunk
    int buf = 0;
    for (int s = 0; s < 12; ++s) {
        if (s + 1 < 12) STAGE(buf ^ 1, s + 1);
        const _Float16* AB = Alds[buf];
        const _Float16* BB = Blds[buf];
        const f16x8 a00 = *(const f16x8*)&AB[(wr + l15) * 64 + pa0];
        const f16x8 a10 = *(const f16x8*)&AB[(wr + 16 + l15) * 64 + pa0];
        const f16x8 b00 = *(const f16x8*)&BB[(wc + l15) * 64 + pa0];
        const f16x8 b10 = *(const f16x8*)&BB[(wc + 16 + l15) * 64 + pa0];
        const f16x8 a01 = *(const f16x8*)&AB[(wr + l15) * 64 + pa1];
        const f16x8 a11 = *(const f16x8*)&AB[(wr + 16 + l15) * 64 + pa1];
        const f16x8 b01 = *(const f16x8*)&BB[(wc + l15) * 64 + pa1];
        const f16x8 b11 = *(const f16x8*)&BB[(wc + 16 + l15) * 64 + pa1];
        acc[0][0] = __builtin_amdgcn_mfma_f32_16x16x32_f16(a00, b00, acc[0][0], 0, 0, 0);
        acc[0][1] = __builtin_amdgcn_mfma_f32_16x16x32_f16(a00, b10, acc[0][1], 0, 0, 0);
        acc[1][0] = __builtin_amdgcn_mfma_f32_16x16x32_f16(a10, b00, acc[1][0], 0, 0, 0);
        acc[1][1] = __builtin_amdgcn_mfma_f32_16x16x32_f16(a10, b10, acc[1][1], 0, 0, 0);
        acc[0][0] = __builtin_amdgcn_mfma_f32_16x16x32_f16(a01, b01, acc[0][0], 0, 0, 0);
        acc[0][1] = __builtin_amdgcn_mfma_f32_16x16x32_f16(a01, b11, acc[0][1], 0, 0, 0);
        acc[1][0] = __builtin_amdgcn_mfma_f32_16x16x32_f16(a11, b01, acc[1][0], 0, 0, 0);
        acc[1][1] = __builtin_amdgcn_mfma_f32_16x16x32_f16(a11, b11, acc[1][1], 0, 0, 0);
        asm volatile("s_waitcnt vmcnt(0)" ::: "memory");
        __builtin_amdgcn_s_barrier();
        buf ^= 1;
    }

    // epilogue: C/D mapping col=lane&15, row=(lane>>4)*4+reg
#pragma unroll
    for (int fi = 0; fi < 2; ++fi) {
#pragma unroll
        for (int fj = 0; fj < 2; ++fj) {
            const int col  = col0 + wc + fj * 16 + l15;
            const int rowb = row0 + wr + fi * 16 + l4 * 4;
            const float bv = bias[col];
#pragma unroll
            for (int j = 0; j < 4; ++j) {
                float v = acc[fi][fj][j] + bv;
                const int r = rowb + j;
                if (EPI == 1) v = 1.f / (1.f + expf(-v));
                if (EPI == 2) {
                    if (col < 2 * Dc) {
                        float t = v;
                        if (col >= Dc) t *= gate[(size_t)r * Dc + (col - Dc)];
                        v = t > 0.f ? t + 1.f : expf(t);
                    }
                }
                C[(size_t)r * N + col] = v;
            }
        }
    }
}

// ---------------------------------------------------------------------------
// Phase A: chunk-local KV state = K_c^T @ V_c (64x64) and ksum (unchanged)
// ---------------------------------------------------------------------------
__global__ __launch_bounds__(256) void chunk_kv(const float* __restrict__ qkv,
                                                float* __restrict__ cbuf) {
    const int c = blockIdx.x, bh = blockIdx.y;
    const int b = bh / Hc, h = bh % Hc;
    const int tid = threadIdx.x;
    const int e  = tid & 63;
    const int g4 = tid >> 6;
    const int d0 = g4 * 16;

    __shared__ float Ks[CS][DHc];

    const size_t row0  = (size_t)b * Lc + c * CS;
    const size_t qbase = row0 * (3 * Dc) + h * DHc;
#pragma unroll
    for (int j = 0; j < 4; ++j) {
        const int fi = tid + j * 256;
        const int r  = fi >> 4;
        const int c4 = (fi & 15) * 4;
        *reinterpret_cast<float4*>(&Ks[r][c4]) =
            *reinterpret_cast<const float4*>(&qkv[qbase + (size_t)r * 3 * Dc + Dc + c4]);
    }
    __syncthreads();

    float S[16];
#pragma unroll
    for (int i = 0; i < 16; ++i) S[i] = 0.f;
    float ksum = 0.f;
    for (int lq = 0; lq < CS; ++lq) {
        const float vv = qkv[qbase + (size_t)lq * 3 * Dc + 2 * Dc + e];
        if (g4 == 0) ksum += Ks[lq][e];
#pragma unroll
        for (int i4 = 0; i4 < 4; ++i4) {
            const float4 k4 = *reinterpret_cast<const float4*>(&Ks[lq][d0 + i4 * 4]);
            S[i4 * 4 + 0] = fmaf(k4.x, vv, S[i4 * 4 + 0]);
            S[i4 * 4 + 1] = fmaf(k4.y, vv, S[i4 * 4 + 1]);
            S[i4 * 4 + 2] = fmaf(k4.z, vv, S[i4 * 4 + 2]);
            S[i4 * 4 + 3] = fmaf(k4.w, vv, S[i4 * 4 + 3]);
        }
    }
    float* out = cbuf + ((size_t)bh * NC + c) * STATE;
#pragma unroll
    for (int i = 0; i < 16; ++i) out[(d0 + i) * DHc + e] = S[i];
    if (g4 == 0) out[DHc * DHc + e] = ksum;
}

// ---------------------------------------------------------------------------
// Phase B: exclusive prefix scan over NC chunk states (unchanged)
// ---------------------------------------------------------------------------
__global__ __launch_bounds__(256) void scan_kernel(float* __restrict__ cbuf) {
    const int idx = blockIdx.x * 256 + threadIdx.x;
    if (idx >= STATE) return;
    float* base = cbuf + (size_t)blockIdx.y * NC * STATE + idx;
    float r = 0.f;
    for (int c = 0; c < NC; ++c) {
        const float cur = base[(size_t)c * STATE];
        base[(size_t)c * STATE] = r;
        r += cur;
    }
}

// ---------------------------------------------------------------------------
// Phase C (matrix form) -> writes attn as f16
// ---------------------------------------------------------------------------
__global__ __launch_bounds__(256) void chunk_qkv_out(const float* __restrict__ qkv,
                                                     const float* __restrict__ cbuf,
                                                     _Float16* __restrict__ attnh) {
    const int c = blockIdx.x, bh = blockIdx.y;
    const int b = bh / Hc, h = bh % Hc;
    const int tid = threadIdx.x;
    const int e  = tid & 63;
    const int g4 = tid >> 6;
    const int l0 = g4 * 16;

    __shared__ float Qs[64][68];
    __shared__ float Kt[64][65];
    __shared__ float Ss[64][68];
    __shared__ float dq[64];

    const size_t row0  = (size_t)b * Lc + c * CS;
    const size_t qbase = row0 * (3 * Dc) + h * DHc;

#pragma unroll
    for (int j = 0; j < 4; ++j) {
        const int fi = tid + j * 256;
        const int r  = fi >> 4;
        const int c4 = (fi & 15) * 4;
        const float4 q4 = *reinterpret_cast<const float4*>(
            &qkv[qbase + (size_t)r * 3 * Dc + c4]);
        *reinterpret_cast<float4*>(&Qs[r][c4]) = q4;
        const float4 k4 = *reinterpret_cast<const float4*>(
            &qkv[qbase + (size_t)r * 3 * Dc + Dc + c4]);
        Kt[c4 + 0][r] = k4.x;
        Kt[c4 + 1][r] = k4.y;
        Kt[c4 + 2][r] = k4.z;
        Kt[c4 + 3][r] = k4.w;
    }
    __syncthreads();

    const float* Pp  = cbuf + ((size_t)bh * NC + c) * STATE;
    const float* kcP = Pp + DHc * DHc;

    float acc[16];
#pragma unroll
    for (int i = 0; i < 16; ++i) acc[i] = 0.f;
#pragma unroll 4
    for (int d4 = 0; d4 < 16; ++d4) {
        const float k0 = Kt[d4 * 4 + 0][e];
        const float k1 = Kt[d4 * 4 + 1][e];
        const float k2 = Kt[d4 * 4 + 2][e];
        const float k3 = Kt[d4 * 4 + 3][e];
#pragma unroll
        for (int i = 0; i < 16; ++i) {
            const float4 q4 = *reinterpret_cast<const float4*>(&Qs[l0 + i][d4 * 4]);
            acc[i] = fmaf(q4.x, k0, acc[i]);
            acc[i] = fmaf(q4.y, k1, acc[i]);
            acc[i] = fmaf(q4.z, k2, acc[i]);
            acc[i] = fmaf(q4.w, k3, acc[i]);
        }
    }
    float den[16];
#pragma unroll
    for (int i = 0; i < 16; ++i) {
        const float m = (e <= l0 + i) ? acc[i] : 0.f;
        Ss[l0 + i][e] = m;
        float r = m;
#pragma unroll
        for (int off = 32; off > 0; off >>= 1) r += __shfl_xor(r, off, 64);
        den[i] = r;
    }
    if (g4 == 0) {
        float s = 0.f;
#pragma unroll 8
        for (int d = 0; d < 64; ++d) s = fmaf(Qs[e][d], kcP[d], s);
        dq[e] = s;
    }
    __syncthreads();

    float num[16];
#pragma unroll
    for (int i = 0; i < 16; ++i) num[i] = 0.f;
#pragma unroll 4
    for (int d4 = 0; d4 < 16; ++d4) {
        const float p0 = Pp[(d4 * 4 + 0) * DHc + e];
        const float p1 = Pp[(d4 * 4 + 1) * DHc + e];
        const float p2 = Pp[(d4 * 4 + 2) * DHc + e];
        const float p3 = Pp[(d4 * 4 + 3) * DHc + e];
#pragma unroll
        for (int i = 0; i < 16; ++i) {
            const float4 q4 = *reinterpret_cast<const float4*>(&Qs[l0 + i][d4 * 4]);
            num[i] = fmaf(q4.x, p0, num[i]);
            num[i] = fmaf(q4.y, p1, num[i]);
            num[i] = fmaf(q4.z, p2, num[i]);
            num[i] = fmaf(q4.w, p3, num[i]);
        }
    }
#pragma unroll 4
    for (int j4 = 0; j4 < 16; ++j4) {
        const float v0 = qkv[qbase + (size_t)(j4 * 4 + 0) * 3 * Dc + 2 * Dc + e];
        const float v1 = qkv[qbase + (size_t)(j4 * 4 + 1) * 3 * Dc + 2 * Dc + e];
        const float v2 = qkv[qbase + (size_t)(j4 * 4 + 2) * 3 * Dc + 2 * Dc + e];
        const float v3 = qkv[qbase + (size_t)(j4 * 4 + 3) * 3 * Dc + 2 * Dc + e];
#pragma unroll
        for (int i = 0; i < 16; ++i) {
            const float4 s4 = *reinterpret_cast<const float4*>(&Ss[l0 + i][j4 * 4]);
            num[i] = fmaf(s4.x, v0, num[i]);
            num[i] = fmaf(s4.y, v1, num[i]);
            num[i] = fmaf(s4.z, v2, num[i]);
            num[i] = fmaf(s4.w, v3, num[i]);
        }
    }
#pragma unroll
    for (int i = 0; i < 16; ++i) {
        const float dd = den[i] + dq[l0 + i] + 1e-6f;
        const size_t oidx = (row0 + l0 + i) * Dc + h * DHc + e;
        attnh[oidx] = (_Float16)(num[i] / dd);
    }
}

// ---------------------------------------------------------------------------
extern "C" void kernel_launch(void* const* d_in, const int* in_sizes, int n_in,
                              void* d_out, int out_size, void* d_ws, size_t ws_size,
                              hipStream_t stream) {
    const float* x      = (const float*)d_in[0];
    const float* W_qkv  = (const float*)d_in[1];
    const float* b_qkv  = (const float*)d_in[2];
    const float* W_gate = (const float*)d_in[3];
    const float* b_gate = (const float*)d_in[4];
    const float* W_proj = (const float*)d_in[5];
    const float* b_proj = (const float*)d_in[6];
    const float* ln_g   = (const float*)d_in[7];
    const float* ln_b   = (const float*)d_in[8];

    float* out_proj = (float*)d_out;           // (B,L,D)
    float* out_gate = out_proj + (size_t)BLD;  // (B,L,D)

    float* ws  = (float*)d_ws;
    float* qkv = ws;                                   // 3*BLD fp32 (featurized)
    _Float16* xh  = (_Float16*)(ws + (size_t)3 * BLD); // BLD
    _Float16* xnh = xh + (size_t)BLD;                  // BLD
    _Float16* wqh = xnh + (size_t)BLD;                 // 3*Dc*Dc = 1,769,472
    _Float16* wgh = wqh + (size_t)3 * Dc * Dc;         // Dc*Dc
    _Float16* wph = wgh + (size_t)Dc * Dc;             // Dc*Dc
    float* cbuf = (float*)(wph + (size_t)Dc * Dc);     // B*H*NC*STATE floats
    _Float16* attnh = wqh;                             // alias: wq dead after qkv gemm

    // 1) weight transposes -> f16 (one launch)
    transpose_all<<<2880, 256, 0, stream>>>(W_gate, W_qkv, W_proj, wgh, wqh, wph);
    // 2) LayerNorm + f16 copies of x, xn
    ln_kernel<<<Mrows, 256, 0, stream>>>(x, ln_g, ln_b, xh, xnh);
    // 3) gate = sigmoid(x @ W_gate + b_gate)
    gemm_f16<1><<<dim3(Dc / 64, Mrows / 64), 256, 0, stream>>>(
        xh, wgh, b_gate, nullptr, out_gate, Dc);
    // 4) qkv = xn @ W_qkv + b_qkv, featurized epilogue
    gemm_f16<2><<<dim3(3 * Dc / 64, Mrows / 64), 256, 0, stream>>>(
        xnh, wqh, b_qkv, out_gate, qkv, 3 * Dc);
    // 5-7) chunked causal linear attention
    chunk_kv<<<dim3(NC, Bc * Hc), 256, 0, stream>>>(qkv, cbuf);
    scan_kernel<<<dim3(17, Bc * Hc), 256, 0, stream>>>(cbuf);
    chunk_qkv_out<<<dim3(NC, Bc * Hc), 256, 0, stream>>>(qkv, cbuf, attnh);
    // 8) out = attn @ W_proj + b_proj
    gemm_f16<0><<<dim3(Dc / 64, Mrows / 64), 256, 0, stream>>>(
        attnh, wph, b_proj, nullptr, out_proj, Dc);
}

// Round 11
// 172.248 us; speedup vs baseline: 4.1043x; 1.0840x over previous
//
#include <hip/hip_runtime.h>
#include <hip/hip_bf16.h>
#include <math.h>

#define Bc 2
#define Lc 1024
#define Dc 768
#define Hc 12
#define DHc 64
#define BLD (Bc * Lc * Dc)   // 1,572,864
#define Mrows (Bc * Lc)      // 2048
#define CS 64
#define NC (Lc / CS)         // 16
#define STATE (DHc * DHc + DHc)  // 4160
#define NQKV 2304
#define NALL 3072

using f32x4  = __attribute__((ext_vector_type(4))) float;
using f16x8  = __attribute__((ext_vector_type(8))) _Float16;
typedef unsigned int u32;

__device__ __forceinline__ void gll16(const void* g, void* l) {
    __builtin_amdgcn_global_load_lds(
        (const __attribute__((address_space(1))) u32*)g,
        (__attribute__((address_space(3))) u32*)l, 16, 0, 0);
}

// ---------------------------------------------------------------------------
// Prep: blocks [0,2880) = weight transposes fp32->f16 (gate|qkv into wAll,
// proj into wph); blocks [2880, 2880+2048) = LayerNorm rows -> xh, xnh (f16).
// ---------------------------------------------------------------------------
__device__ __forceinline__ void tsp_tile(const float* __restrict__ W,
                                         _Float16* __restrict__ Wh,
                                         int N, int bx, int by, int tid) {
    __shared__ float t[32][33];
    const int tx = tid & 31, ty = tid >> 5;  // ty 0..7
#pragma unroll
    for (int j = 0; j < 4; ++j)
        t[ty + 8 * j][tx] = W[(size_t)(by * 32 + ty + 8 * j) * N + bx * 32 + tx];
    __syncthreads();
#pragma unroll
    for (int j = 0; j < 4; ++j) {
        const size_t o = (size_t)(bx * 32 + ty + 8 * j) * Dc + by * 32 + tx;
        Wh[o] = (_Float16)t[tx][ty + 8 * j];
    }
}

__global__ __launch_bounds__(256) void prep_kernel(const float* __restrict__ Wg,
                                                   const float* __restrict__ Wq,
                                                   const float* __restrict__ Wp,
                                                   const float* __restrict__ x,
                                                   const float* __restrict__ lg,
                                                   const float* __restrict__ lb,
                                                   _Float16* __restrict__ wAll,
                                                   _Float16* __restrict__ wph,
                                                   _Float16* __restrict__ xh,
                                                   _Float16* __restrict__ xnh) {
    const int bid = blockIdx.x;
    const int tid = threadIdx.x;
    if (bid < 576) {
        tsp_tile(Wg, wAll, Dc, bid % 24, bid / 24, tid);
        return;
    } else if (bid < 2304) {
        const int b = bid - 576;
        tsp_tile(Wq, wAll + (size_t)Dc * Dc, NQKV, b % 72, b / 72, tid);
        return;
    } else if (bid < 2880) {
        const int b = bid - 2304;
        tsp_tile(Wp, wph, Dc, b % 24, b / 24, tid);
        return;
    }
    // ---- LayerNorm ----
    const int row = bid - 2880;
    const float* xr = x + (size_t)row * Dc;
    float v[3];
    float s = 0.f, ss = 0.f;
#pragma unroll
    for (int i = 0; i < 3; ++i) {
        v[i] = xr[tid + i * 256];
        s += v[i];
        ss += v[i] * v[i];
    }
#pragma unroll
    for (int off = 32; off > 0; off >>= 1) {
        s  += __shfl_down(s, off, 64);
        ss += __shfl_down(ss, off, 64);
    }
    __shared__ float sw[2][4];
    const int wave = tid >> 6;
    const int lane = tid & 63;
    if (lane == 0) { sw[0][wave] = s; sw[1][wave] = ss; }
    __syncthreads();
    s  = sw[0][0] + sw[0][1] + sw[0][2] + sw[0][3];
    ss = sw[1][0] + sw[1][1] + sw[1][2] + sw[1][3];
    const float mu = s * (1.f / Dc);
    const float var = ss * (1.f / Dc) - mu * mu;
    const float rstd = rsqrtf(var + 1e-5f);
    const size_t base = (size_t)row * Dc;
#pragma unroll
    for (int i = 0; i < 3; ++i) {
        const int c = tid + i * 256;
        xh[base + c] = (_Float16)v[i];
        xnh[base + c] = (_Float16)((v[i] - mu) * rstd * lg[c] + lb[c]);
    }
}

// ---------------------------------------------------------------------------
// Merged gate|qkv f16 GEMM over N=3072 virtual columns. K=768, 12 stages.
// cols [0,768): A=xh, sigmoid -> out_gate fp32
// cols [768,3072): A=xnh; q cols get elu+1; k,v raw -> qkvh f16
// Round-5-proven structure: 64x64 tile, 4 waves 2x2, BK=64, dbuf
// global_load_lds, XOR chunk swizzle on source + ds_read.
// ---------------------------------------------------------------------------
__global__ __launch_bounds__(256) void gemm_gq(const _Float16* __restrict__ xh,
                                               const _Float16* __restrict__ xnh,
                                               const _Float16* __restrict__ wAll,
                                               const float* __restrict__ b_gate,
                                               const float* __restrict__ b_qkv,
                                               float* __restrict__ out_gate,
                                               _Float16* __restrict__ qkvh) {
    __shared__ _Float16 Alds[2][64 * 64];
    __shared__ _Float16 Blds[2][64 * 64];
    const int tid  = threadIdx.x;
    const int lane = tid & 63;
    const int wv  = tid >> 6;
    const int wr  = (wv >> 1) * 32;
    const int wc  = (wv & 1) * 32;
    const int l15 = lane & 15;
    const int l4  = lane >> 4;
    const int r8  = lane >> 3;
    const int ch  = lane & 7;
    const int sChunk = ((ch ^ r8) * 8);
    const int row0 = blockIdx.y * 64;
    const int col0 = blockIdx.x * 64;
    const bool is_gate = col0 < Dc;
    const _Float16* A = is_gate ? xh : xnh;

    f32x4 acc[2][2];
    const f32x4 zero = {0.f, 0.f, 0.f, 0.f};
#pragma unroll
    for (int i = 0; i < 2; ++i)
#pragma unroll
        for (int j = 0; j < 2; ++j) acc[i][j] = zero;

    auto STAGE = [&](int buf, int s) {
        const _Float16* as = A + (size_t)(row0 + 16 * wv + r8) * 768 + s * 64 + sChunk;
        gll16(as,           &Alds[buf][(16 * wv) * 64]);
        gll16(as + 8 * 768, &Alds[buf][(16 * wv + 8) * 64]);
        const _Float16* bs = wAll + (size_t)(col0 + 16 * wv + r8) * 768 + s * 64 + sChunk;
        gll16(bs,           &Blds[buf][(16 * wv) * 64]);
        gll16(bs + 8 * 768, &Blds[buf][(16 * wv + 8) * 64]);
    };

    STAGE(0, 0);
    asm volatile("s_waitcnt vmcnt(0)" ::: "memory");
    __builtin_amdgcn_s_barrier();

    const int pa0 = ((l4)     ^ (l15 & 7)) * 8;
    const int pa1 = ((4 + l4) ^ (l15 & 7)) * 8;
    int buf = 0;
    for (int s = 0; s < 12; ++s) {
        if (s + 1 < 12) STAGE(buf ^ 1, s + 1);
        const _Float16* AB = Alds[buf];
        const _Float16* BB = Blds[buf];
        const f16x8 a00 = *(const f16x8*)&AB[(wr + l15) * 64 + pa0];
        const f16x8 a10 = *(const f16x8*)&AB[(wr + 16 + l15) * 64 + pa0];
        const f16x8 b00 = *(const f16x8*)&BB[(wc + l15) * 64 + pa0];
        const f16x8 b10 = *(const f16x8*)&BB[(wc + 16 + l15) * 64 + pa0];
        const f16x8 a01 = *(const f16x8*)&AB[(wr + l15) * 64 + pa1];
        const f16x8 a11 = *(const f16x8*)&AB[(wr + 16 + l15) * 64 + pa1];
        const f16x8 b01 = *(const f16x8*)&BB[(wc + l15) * 64 + pa1];
        const f16x8 b11 = *(const f16x8*)&BB[(wc + 16 + l15) * 64 + pa1];
        acc[0][0] = __builtin_amdgcn_mfma_f32_16x16x32_f16(a00, b00, acc[0][0], 0, 0, 0);
        acc[0][1] = __builtin_amdgcn_mfma_f32_16x16x32_f16(a00, b10, acc[0][1], 0, 0, 0);
        acc[1][0] = __builtin_amdgcn_mfma_f32_16x16x32_f16(a10, b00, acc[1][0], 0, 0, 0);
        acc[1][1] = __builtin_amdgcn_mfma_f32_16x16x32_f16(a10, b10, acc[1][1], 0, 0, 0);
        acc[0][0] = __builtin_amdgcn_mfma_f32_16x16x32_f16(a01, b01, acc[0][0], 0, 0, 0);
        acc[0][1] = __builtin_amdgcn_mfma_f32_16x16x32_f16(a01, b11, acc[0][1], 0, 0, 0);
        acc[1][0] = __builtin_amdgcn_mfma_f32_16x16x32_f16(a11, b01, acc[1][0], 0, 0, 0);
        acc[1][1] = __builtin_amdgcn_mfma_f32_16x16x32_f16(a11, b11, acc[1][1], 0, 0, 0);
        asm volatile("s_waitcnt vmcnt(0)" ::: "memory");
        __builtin_amdgcn_s_barrier();
        buf ^= 1;
    }

    const float* bptr = is_gate ? b_gate : (b_qkv - Dc);
#pragma unroll
    for (int fi = 0; fi < 2; ++fi) {
#pragma unroll
        for (int fj = 0; fj < 2; ++fj) {
            const int col  = col0 + wc + fj * 16 + l15;
            const int rowb = row0 + wr + fi * 16 + l4 * 4;
            const float bv = bptr[col];
#pragma unroll
            for (int j = 0; j < 4; ++j) {
                float v = acc[fi][fj][j] + bv;
                const size_t r = rowb + j;
                if (is_gate) {
                    out_gate[r * Dc + col] = 1.f / (1.f + expf(-v));
                } else {
                    const int cq = col - Dc;
                    if (cq < Dc) v = v > 0.f ? v + 1.f : expf(v);  // q featurize
                    qkvh[r * NQKV + cq] = (_Float16)v;
                }
            }
        }
    }
}

// ---------------------------------------------------------------------------
// Phase A: chunk KV state = K_f^T @ V (64x64) + ksum. k featurized at staging.
// ---------------------------------------------------------------------------
__global__ __launch_bounds__(256) void chunk_kv(const _Float16* __restrict__ qkvh,
                                                const float* __restrict__ gate,
                                                float* __restrict__ cbuf) {
    const int c = blockIdx.x, bh = blockIdx.y;
    const int b = bh / Hc, h = bh % Hc;
    const int tid = threadIdx.x;
    const int e  = tid & 63;
    const int g4 = tid >> 6;
    const int d0 = g4 * 16;

    __shared__ float Ks[CS][DHc];

    const size_t row0  = (size_t)b * Lc + c * CS;
    const size_t qbase = row0 * NQKV + h * DHc;
    const size_t gbase = row0 * Dc + h * DHc;
#pragma unroll
    for (int j = 0; j < 2; ++j) {
        const int fi = tid + j * 256;   // 0..511 octets
        const int r  = fi >> 3;
        const int c8 = (fi & 7) * 8;
        const f16x8 k8 = *reinterpret_cast<const f16x8*>(
            &qkvh[qbase + (size_t)r * NQKV + Dc + c8]);
        const float4 g0 = *reinterpret_cast<const float4*>(&gate[gbase + (size_t)r * Dc + c8]);
        const float4 g1 = *reinterpret_cast<const float4*>(&gate[gbase + (size_t)r * Dc + c8 + 4]);
        const float gg[8] = {g0.x, g0.y, g0.z, g0.w, g1.x, g1.y, g1.z, g1.w};
#pragma unroll
        for (int i = 0; i < 8; ++i) {
            const float t = (float)k8[i] * gg[i];
            Ks[r][c8 + i] = t > 0.f ? t + 1.f : expf(t);
        }
    }
    __syncthreads();

    float S[16];
#pragma unroll
    for (int i = 0; i < 16; ++i) S[i] = 0.f;
    float ksum = 0.f;
    for (int lq = 0; lq < CS; ++lq) {
        const float vv = (float)qkvh[qbase + (size_t)lq * NQKV + 2 * Dc + e];
        if (g4 == 0) ksum += Ks[lq][e];
#pragma unroll
        for (int i4 = 0; i4 < 4; ++i4) {
            const float4 k4 = *reinterpret_cast<const float4*>(&Ks[lq][d0 + i4 * 4]);
            S[i4 * 4 + 0] = fmaf(k4.x, vv, S[i4 * 4 + 0]);
            S[i4 * 4 + 1] = fmaf(k4.y, vv, S[i4 * 4 + 1]);
            S[i4 * 4 + 2] = fmaf(k4.z, vv, S[i4 * 4 + 2]);
            S[i4 * 4 + 3] = fmaf(k4.w, vv, S[i4 * 4 + 3]);
        }
    }
    float* out = cbuf + ((size_t)bh * NC + c) * STATE;
#pragma unroll
    for (int i = 0; i < 16; ++i) out[(d0 + i) * DHc + e] = S[i];
    if (g4 == 0) out[DHc * DHc + e] = ksum;
}

// ---------------------------------------------------------------------------
// Phase B: exclusive prefix scan over NC chunk states (unchanged)
// ---------------------------------------------------------------------------
__global__ __launch_bounds__(256) void scan_kernel(float* __restrict__ cbuf) {
    const int idx = blockIdx.x * 256 + threadIdx.x;
    if (idx >= STATE) return;
    float* base = cbuf + (size_t)blockIdx.y * NC * STATE + idx;
    float r = 0.f;
    for (int c = 0; c < NC; ++c) {
        const float cur = base[(size_t)c * STATE];
        base[(size_t)c * STATE] = r;
        r += cur;
    }
}

// ---------------------------------------------------------------------------
// Phase C (matrix form), f16 in / f16 out; k featurized at staging
// ---------------------------------------------------------------------------
__global__ __launch_bounds__(256) void chunk_qkv_out(const _Float16* __restrict__ qkvh,
                                                     const float* __restrict__ gate,
                                                     const float* __restrict__ cbuf,
                                                     _Float16* __restrict__ attnh) {
    const int c = blockIdx.x, bh = blockIdx.y;
    const int b = bh / Hc, h = bh % Hc;
    const int tid = threadIdx.x;
    const int e  = tid & 63;
    const int g4 = tid >> 6;
    const int l0 = g4 * 16;

    __shared__ float Qs[64][68];
    __shared__ float Kt[64][65];
    __shared__ float Ss[64][68];
    __shared__ float dq[64];

    const size_t row0  = (size_t)b * Lc + c * CS;
    const size_t qbase = row0 * NQKV + h * DHc;
    const size_t gbase = row0 * Dc + h * DHc;

#pragma unroll
    for (int j = 0; j < 2; ++j) {
        const int fi = tid + j * 256;
        const int r  = fi >> 3;
        const int c8 = (fi & 7) * 8;
        const f16x8 q8 = *reinterpret_cast<const f16x8*>(&qkvh[qbase + (size_t)r * NQKV + c8]);
#pragma unroll
        for (int i = 0; i < 8; ++i) Qs[r][c8 + i] = (float)q8[i];
        const f16x8 k8 = *reinterpret_cast<const f16x8*>(
            &qkvh[qbase + (size_t)r * NQKV + Dc + c8]);
        const float4 g0 = *reinterpret_cast<const float4*>(&gate[gbase + (size_t)r * Dc + c8]);
        const float4 g1 = *reinterpret_cast<const float4*>(&gate[gbase + (size_t)r * Dc + c8 + 4]);
        const float gg[8] = {g0.x, g0.y, g0.z, g0.w, g1.x, g1.y, g1.z, g1.w};
#pragma unroll
        for (int i = 0; i < 8; ++i) {
            const float t = (float)k8[i] * gg[i];
            Kt[c8 + i][r] = t > 0.f ? t + 1.f : expf(t);
        }
    }
    __syncthreads();

    const float* Pp  = cbuf + ((size_t)bh * NC + c) * STATE;
    const float* kcP = Pp + DHc * DHc;

    float acc[16];
#pragma unroll
    for (int i = 0; i < 16; ++i) acc[i] = 0.f;
#pragma unroll 4
    for (int d4 = 0; d4 < 16; ++d4) {
        const float k0 = Kt[d4 * 4 + 0][e];
        const float k1 = Kt[d4 * 4 + 1][e];
        const float k2 = Kt[d4 * 4 + 2][e];
        const float k3 = Kt[d4 * 4 + 3][e];
#pragma unroll
        for (int i = 0; i < 16; ++i) {
            const float4 q4 = *reinterpret_cast<const float4*>(&Qs[l0 + i][d4 * 4]);
            acc[i] = fmaf(q4.x, k0, acc[i]);
            acc[i] = fmaf(q4.y, k1, acc[i]);
            acc[i] = fmaf(q4.z, k2, acc[i]);
            acc[i] = fmaf(q4.w, k3, acc[i]);
        }
    }
    float den[16];
#pragma unroll
    for (int i = 0; i < 16; ++i) {
        const float m = (e <= l0 + i) ? acc[i] : 0.f;
        Ss[l0 + i][e] = m;
        float r = m;
#pragma unroll
        for (int off = 32; off > 0; off >>= 1) r += __shfl_xor(r, off, 64);
        den[i] = r;
    }
    if (g4 == 0) {
        float s = 0.f;
#pragma unroll 8
        for (int d = 0; d < 64; ++d) s = fmaf(Qs[e][d], kcP[d], s);
        dq[e] = s;
    }
    __syncthreads();

    float num[16];
#pragma unroll
    for (int i = 0; i < 16; ++i) num[i] = 0.f;
#pragma unroll 4
    for (int d4 = 0; d4 < 16; ++d4) {
        const float p0 = Pp[(d4 * 4 + 0) * DHc + e];
        const float p1 = Pp[(d4 * 4 + 1) * DHc + e];
        const float p2 = Pp[(d4 * 4 + 2) * DHc + e];
        const float p3 = Pp[(d4 * 4 + 3) * DHc + e];
#pragma unroll
        for (int i = 0; i < 16; ++i) {
            const float4 q4 = *reinterpret_cast<const float4*>(&Qs[l0 + i][d4 * 4]);
            num[i] = fmaf(q4.x, p0, num[i]);
            num[i] = fmaf(q4.y, p1, num[i]);
            num[i] = fmaf(q4.z, p2, num[i]);
            num[i] = fmaf(q4.w, p3, num[i]);
        }
    }
#pragma unroll 4
    for (int j4 = 0; j4 < 16; ++j4) {
        const float v0 = (float)qkvh[qbase + (size_t)(j4 * 4 + 0) * NQKV + 2 * Dc + e];
        const float v1 = (float)qkvh[qbase + (size_t)(j4 * 4 + 1) * NQKV + 2 * Dc + e];
        const float v2 = (float)qkvh[qbase + (size_t)(j4 * 4 + 2) * NQKV + 2 * Dc + e];
        const float v3 = (float)qkvh[qbase + (size_t)(j4 * 4 + 3) * NQKV + 2 * Dc + e];
#pragma unroll
        for (int i = 0; i < 16; ++i) {
            const float4 s4 = *reinterpret_cast<const float4*>(&Ss[l0 + i][j4 * 4]);
            num[i] = fmaf(s4.x, v0, num[i]);
            num[i] = fmaf(s4.y, v1, num[i]);
            num[i] = fmaf(s4.z, v2, num[i]);
            num[i] = fmaf(s4.w, v3, num[i]);
        }
    }
#pragma unroll
    for (int i = 0; i < 16; ++i) {
        const float dd = den[i] + dq[l0 + i] + 1e-6f;
        const size_t oidx = (row0 + l0 + i) * Dc + h * DHc + e;
        attnh[oidx] = (_Float16)(num[i] / dd);
    }
}

// ---------------------------------------------------------------------------
// proj GEMM: out = attn @ Wp^T + b  (f16 in, fp32 out) — round-5 structure
// ---------------------------------------------------------------------------
__global__ __launch_bounds__(256) void gemm_proj(const _Float16* __restrict__ A,
                                                 const _Float16* __restrict__ B,
                                                 const float* __restrict__ bias,
                                                 float* __restrict__ C) {
    __shared__ _Float16 Alds[2][64 * 64];
    __shared__ _Float16 Blds[2][64 * 64];
    const int tid  = threadIdx.x;
    const int lane = tid & 63;
    const int wv  = tid >> 6;
    const int wr  = (wv >> 1) * 32;
    const int wc  = (wv & 1) * 32;
    const int l15 = lane & 15;
    const int l4  = lane >> 4;
    const int r8  = lane >> 3;
    const int ch  = lane & 7;
    const int sChunk = ((ch ^ r8) * 8);
    const int row0 = blockIdx.y * 64;
    const int col0 = blockIdx.x * 64;

    f32x4 acc[2][2];
    const f32x4 zero = {0.f, 0.f, 0.f, 0.f};
#pragma unroll
    for (int i = 0; i < 2; ++i)
#pragma unroll
        for (int j = 0; j < 2; ++j) acc[i][j] = zero;

    auto STAGE = [&](int buf, int s) {
        const _Float16* as = A + (size_t)(row0 + 16 * wv + r8) * 768 + s * 64 + sChunk;
        gll16(as,           &Alds[buf][(16 * wv) * 64]);
        gll16(as + 8 * 768, &Alds[buf][(16 * wv + 8) * 64]);
        const _Float16* bs = B + (size_t)(col0 + 16 * wv + r8) * 768 + s * 64 + sChunk;
        gll16(bs,           &Blds[buf][(16 * wv) * 64]);
        gll16(bs + 8 * 768, &Blds[buf][(16 * wv + 8) * 64]);
    };

    STAGE(0, 0);
    asm volatile("s_waitcnt vmcnt(0)" ::: "memory");
    __builtin_amdgcn_s_barrier();

    const int pa0 = ((l4)     ^ (l15 & 7)) * 8;
    const int pa1 = ((4 + l4) ^ (l15 & 7)) * 8;
    int buf = 0;
    for (int s = 0; s < 12; ++s) {
        if (s + 1 < 12) STAGE(buf ^ 1, s + 1);
        const _Float16* AB = Alds[buf];
        const _Float16* BB = Blds[buf];
        const f16x8 a00 = *(const f16x8*)&AB[(wr + l15) * 64 + pa0];
        const f16x8 a10 = *(const f16x8*)&AB[(wr + 16 + l15) * 64 + pa0];
        const f16x8 b00 = *(const f16x8*)&BB[(wc + l15) * 64 + pa0];
        const f16x8 b10 = *(const f16x8*)&BB[(wc + 16 + l15) * 64 + pa0];
        const f16x8 a01 = *(const f16x8*)&AB[(wr + l15) * 64 + pa1];
        const f16x8 a11 = *(const f16x8*)&AB[(wr + 16 + l15) * 64 + pa1];
        const f16x8 b01 = *(const f16x8*)&BB[(wc + l15) * 64 + pa1];
        const f16x8 b11 = *(const f16x8*)&BB[(wc + 16 + l15) * 64 + pa1];
        acc[0][0] = __builtin_amdgcn_mfma_f32_16x16x32_f16(a00, b00, acc[0][0], 0, 0, 0);
        acc[0][1] = __builtin_amdgcn_mfma_f32_16x16x32_f16(a00, b10, acc[0][1], 0, 0, 0);
        acc[1][0] = __builtin_amdgcn_mfma_f32_16x16x32_f16(a10, b00, acc[1][0], 0, 0, 0);
        acc[1][1] = __builtin_amdgcn_mfma_f32_16x16x32_f16(a10, b10, acc[1][1], 0, 0, 0);
        acc[0][0] = __builtin_amdgcn_mfma_f32_16x16x32_f16(a01, b01, acc[0][0], 0, 0, 0);
        acc[0][1] = __builtin_amdgcn_mfma_f32_16x16x32_f16(a01, b11, acc[0][1], 0, 0, 0);
        acc[1][0] = __builtin_amdgcn_mfma_f32_16x16x32_f16(a11, b01, acc[1][0], 0, 0, 0);
        acc[1][1] = __builtin_amdgcn_mfma_f32_16x16x32_f16(a11, b11, acc[1][1], 0, 0, 0);
        asm volatile("s_waitcnt vmcnt(0)" ::: "memory");
        __builtin_amdgcn_s_barrier();
        buf ^= 1;
    }

#pragma unroll
    for (int fi = 0; fi < 2; ++fi) {
#pragma unroll
        for (int fj = 0; fj < 2; ++fj) {
            const int col  = col0 + wc + fj * 16 + l15;
            const int rowb = row0 + wr + fi * 16 + l4 * 4;
            const float bv = bias[col];
#pragma unroll
            for (int j = 0; j < 4; ++j)
                C[(size_t)(rowb + j) * Dc + col] = acc[fi][fj][j] + bv;
        }
    }
}

// ---------------------------------------------------------------------------
extern "C" void kernel_launch(void* const* d_in, const int* in_sizes, int n_in,
                              void* d_out, int out_size, void* d_ws, size_t ws_size,
                              hipStream_t stream) {
    const float* x      = (const float*)d_in[0];
    const float* W_qkv  = (const float*)d_in[1];
    const float* b_qkv  = (const float*)d_in[2];
    const float* W_gate = (const float*)d_in[3];
    const float* b_gate = (const float*)d_in[4];
    const float* W_proj = (const float*)d_in[5];
    const float* b_proj = (const float*)d_in[6];
    const float* ln_g   = (const float*)d_in[7];
    const float* ln_b   = (const float*)d_in[8];

    float* out_proj = (float*)d_out;           // (B,L,D)
    float* out_gate = out_proj + (size_t)BLD;  // (B,L,D)

    _Float16* qkvh = (_Float16*)d_ws;                 // 3*BLD
    _Float16* xh   = qkvh + (size_t)3 * BLD;          // BLD
    _Float16* xnh  = xh + (size_t)BLD;                // BLD
    _Float16* wAll = xnh + (size_t)BLD;               // 3072*768
    _Float16* wph  = wAll + (size_t)NALL * Dc;        // 768*768
    float* cbuf    = (float*)(wph + (size_t)Dc * Dc); // B*H*NC*STATE fp32
    _Float16* attnh = wAll;                           // alias: wAll dead after gemm_gq

    // 1) prep: weight transposes + LayerNorm (one launch)
    prep_kernel<<<2880 + Mrows, 256, 0, stream>>>(W_gate, W_qkv, W_proj, x,
                                                  ln_g, ln_b, wAll, wph, xh, xnh);
    // 2) merged gate|qkv GEMM
    gemm_gq<<<dim3(NALL / 64, Mrows / 64), 256, 0, stream>>>(
        xh, xnh, wAll, b_gate, b_qkv, out_gate, qkvh);
    // 3-5) chunked causal linear attention
    chunk_kv<<<dim3(NC, Bc * Hc), 256, 0, stream>>>(qkvh, out_gate, cbuf);
    scan_kernel<<<dim3(17, Bc * Hc), 256, 0, stream>>>(cbuf);
    chunk_qkv_out<<<dim3(NC, Bc * Hc), 256, 0, stream>>>(qkvh, out_gate, cbuf, attnh);
    // 6) out = attn @ W_proj + b_proj
    gemm_proj<<<dim3(Dc / 64, Mrows / 64), 256, 0, stream>>>(
        attnh, wph, b_proj, out_proj);
}

// Round 12
// 135.431 us; speedup vs baseline: 5.2201x; 1.2719x over previous
//
#include <hip/hip_runtime.h>
#include <hip/hip_bf16.h>
#include <math.h>

#define Bc 2
#define Lc 1024
#define Dc 768
#define Hc 12
#define DHc 64
#define BLD (Bc * Lc * Dc)   // 1,572,864
#define Mrows (Bc * Lc)      // 2048
#define CS 64
#define NC (Lc / CS)         // 16
#define STATE (DHc * DHc + DHc)  // 4160
#define NQKV 2304
#define NALL 3072

using f32x4  = __attribute__((ext_vector_type(4))) float;
using f16x8  = __attribute__((ext_vector_type(8))) _Float16;
typedef unsigned int u32;

__device__ __forceinline__ void gll16(const void* g, void* l) {
    __builtin_amdgcn_global_load_lds(
        (const __attribute__((address_space(1))) u32*)g,
        (__attribute__((address_space(3))) u32*)l, 16, 0, 0);
}

// ---------------------------------------------------------------------------
// Prep: blocks [0,2880) = weight transposes fp32->f16 (gate|qkv into wAll,
// proj into wph); blocks [2880, 2880+2048) = LayerNorm rows -> xh, xnh (f16).
// ---------------------------------------------------------------------------
__device__ __forceinline__ void tsp_tile(const float* __restrict__ W,
                                         _Float16* __restrict__ Wh,
                                         int N, int bx, int by, int tid) {
    __shared__ float t[32][33];
    const int tx = tid & 31, ty = tid >> 5;  // ty 0..7
#pragma unroll
    for (int j = 0; j < 4; ++j)
        t[ty + 8 * j][tx] = W[(size_t)(by * 32 + ty + 8 * j) * N + bx * 32 + tx];
    __syncthreads();
#pragma unroll
    for (int j = 0; j < 4; ++j) {
        const size_t o = (size_t)(bx * 32 + ty + 8 * j) * Dc + by * 32 + tx;
        Wh[o] = (_Float16)t[tx][ty + 8 * j];
    }
}

__global__ __launch_bounds__(256) void prep_kernel(const float* __restrict__ Wg,
                                                   const float* __restrict__ Wq,
                                                   const float* __restrict__ Wp,
                                                   const float* __restrict__ x,
                                                   const float* __restrict__ lg,
                                                   const float* __restrict__ lb,
                                                   _Float16* __restrict__ wAll,
                                                   _Float16* __restrict__ wph,
                                                   _Float16* __restrict__ xh,
                                                   _Float16* __restrict__ xnh) {
    const int bid = blockIdx.x;
    const int tid = threadIdx.x;
    if (bid < 576) {
        tsp_tile(Wg, wAll, Dc, bid % 24, bid / 24, tid);
        return;
    } else if (bid < 2304) {
        const int b = bid - 576;
        tsp_tile(Wq, wAll + (size_t)Dc * Dc, NQKV, b % 72, b / 72, tid);
        return;
    } else if (bid < 2880) {
        const int b = bid - 2304;
        tsp_tile(Wp, wph, Dc, b % 24, b / 24, tid);
        return;
    }
    // ---- LayerNorm ----
    const int row = bid - 2880;
    const float* xr = x + (size_t)row * Dc;
    float v[3];
    float s = 0.f, ss = 0.f;
#pragma unroll
    for (int i = 0; i < 3; ++i) {
        v[i] = xr[tid + i * 256];
        s += v[i];
        ss += v[i] * v[i];
    }
#pragma unroll
    for (int off = 32; off > 0; off >>= 1) {
        s  += __shfl_down(s, off, 64);
        ss += __shfl_down(ss, off, 64);
    }
    __shared__ float sw[2][4];
    const int wave = tid >> 6;
    const int lane = tid & 63;
    if (lane == 0) { sw[0][wave] = s; sw[1][wave] = ss; }
    __syncthreads();
    s  = sw[0][0] + sw[0][1] + sw[0][2] + sw[0][3];
    ss = sw[1][0] + sw[1][1] + sw[1][2] + sw[1][3];
    const float mu = s * (1.f / Dc);
    const float var = ss * (1.f / Dc) - mu * mu;
    const float rstd = rsqrtf(var + 1e-5f);
    const size_t base = (size_t)row * Dc;
#pragma unroll
    for (int i = 0; i < 3; ++i) {
        const int c = tid + i * 256;
        xh[base + c] = (_Float16)v[i];
        xnh[base + c] = (_Float16)((v[i] - mu) * rstd * lg[c] + lb[c]);
    }
}

// ---------------------------------------------------------------------------
// Merged gate|qkv f16 GEMM (unchanged from round 11 — passed)
// ---------------------------------------------------------------------------
__global__ __launch_bounds__(256) void gemm_gq(const _Float16* __restrict__ xh,
                                               const _Float16* __restrict__ xnh,
                                               const _Float16* __restrict__ wAll,
                                               const float* __restrict__ b_gate,
                                               const float* __restrict__ b_qkv,
                                               float* __restrict__ out_gate,
                                               _Float16* __restrict__ qkvh) {
    __shared__ _Float16 Alds[2][64 * 64];
    __shared__ _Float16 Blds[2][64 * 64];
    const int tid  = threadIdx.x;
    const int lane = tid & 63;
    const int wv  = tid >> 6;
    const int wr  = (wv >> 1) * 32;
    const int wc  = (wv & 1) * 32;
    const int l15 = lane & 15;
    const int l4  = lane >> 4;
    const int r8  = lane >> 3;
    const int ch  = lane & 7;
    const int sChunk = ((ch ^ r8) * 8);
    const int row0 = blockIdx.y * 64;
    const int col0 = blockIdx.x * 64;
    const bool is_gate = col0 < Dc;
    const _Float16* A = is_gate ? xh : xnh;

    f32x4 acc[2][2];
    const f32x4 zero = {0.f, 0.f, 0.f, 0.f};
#pragma unroll
    for (int i = 0; i < 2; ++i)
#pragma unroll
        for (int j = 0; j < 2; ++j) acc[i][j] = zero;

    auto STAGE = [&](int buf, int s) {
        const _Float16* as = A + (size_t)(row0 + 16 * wv + r8) * 768 + s * 64 + sChunk;
        gll16(as,           &Alds[buf][(16 * wv) * 64]);
        gll16(as + 8 * 768, &Alds[buf][(16 * wv + 8) * 64]);
        const _Float16* bs = wAll + (size_t)(col0 + 16 * wv + r8) * 768 + s * 64 + sChunk;
        gll16(bs,           &Blds[buf][(16 * wv) * 64]);
        gll16(bs + 8 * 768, &Blds[buf][(16 * wv + 8) * 64]);
    };

    STAGE(0, 0);
    asm volatile("s_waitcnt vmcnt(0)" ::: "memory");
    __builtin_amdgcn_s_barrier();

    const int pa0 = ((l4)     ^ (l15 & 7)) * 8;
    const int pa1 = ((4 + l4) ^ (l15 & 7)) * 8;
    int buf = 0;
    for (int s = 0; s < 12; ++s) {
        if (s + 1 < 12) STAGE(buf ^ 1, s + 1);
        const _Float16* AB = Alds[buf];
        const _Float16* BB = Blds[buf];
        const f16x8 a00 = *(const f16x8*)&AB[(wr + l15) * 64 + pa0];
        const f16x8 a10 = *(const f16x8*)&AB[(wr + 16 + l15) * 64 + pa0];
        const f16x8 b00 = *(const f16x8*)&BB[(wc + l15) * 64 + pa0];
        const f16x8 b10 = *(const f16x8*)&BB[(wc + 16 + l15) * 64 + pa0];
        const f16x8 a01 = *(const f16x8*)&AB[(wr + l15) * 64 + pa1];
        const f16x8 a11 = *(const f16x8*)&AB[(wr + 16 + l15) * 64 + pa1];
        const f16x8 b01 = *(const f16x8*)&BB[(wc + l15) * 64 + pa1];
        const f16x8 b11 = *(const f16x8*)&BB[(wc + 16 + l15) * 64 + pa1];
        acc[0][0] = __builtin_amdgcn_mfma_f32_16x16x32_f16(a00, b00, acc[0][0], 0, 0, 0);
        acc[0][1] = __builtin_amdgcn_mfma_f32_16x16x32_f16(a00, b10, acc[0][1], 0, 0, 0);
        acc[1][0] = __builtin_amdgcn_mfma_f32_16x16x32_f16(a10, b00, acc[1][0], 0, 0, 0);
        acc[1][1] = __builtin_amdgcn_mfma_f32_16x16x32_f16(a10, b10, acc[1][1], 0, 0, 0);
        acc[0][0] = __builtin_amdgcn_mfma_f32_16x16x32_f16(a01, b01, acc[0][0], 0, 0, 0);
        acc[0][1] = __builtin_amdgcn_mfma_f32_16x16x32_f16(a01, b11, acc[0][1], 0, 0, 0);
        acc[1][0] = __builtin_amdgcn_mfma_f32_16x16x32_f16(a11, b01, acc[1][0], 0, 0, 0);
        acc[1][1] = __builtin_amdgcn_mfma_f32_16x16x32_f16(a11, b11, acc[1][1], 0, 0, 0);
        asm volatile("s_waitcnt vmcnt(0)" ::: "memory");
        __builtin_amdgcn_s_barrier();
        buf ^= 1;
    }

    const float* bptr = is_gate ? b_gate : (b_qkv - Dc);
#pragma unroll
    for (int fi = 0; fi < 2; ++fi) {
#pragma unroll
        for (int fj = 0; fj < 2; ++fj) {
            const int col  = col0 + wc + fj * 16 + l15;
            const int rowb = row0 + wr + fi * 16 + l4 * 4;
            const float bv = bptr[col];
#pragma unroll
            for (int j = 0; j < 4; ++j) {
                float v = acc[fi][fj][j] + bv;
                const size_t r = rowb + j;
                if (is_gate) {
                    out_gate[r * Dc + col] = 1.f / (1.f + expf(-v));
                } else {
                    const int cq = col - Dc;
                    if (cq < Dc) v = v > 0.f ? v + 1.f : expf(v);  // q featurize
                    qkvh[r * NQKV + cq] = (_Float16)v;
                }
            }
        }
    }
}

// ---------------------------------------------------------------------------
// Phase A (MFMA): S_T[e][d] = sum_j V[j][e]*K_f[j][d]; ksum[d].
// Stage Kt[d][j], Vt[e][j] transposed; 4 waves, wave w owns e rows w*16..+16.
// Output stored TRANSPOSED [e][d] so downstream P is row-major for B-frags.
// ---------------------------------------------------------------------------
__global__ __launch_bounds__(256) void chunk_kv(const _Float16* __restrict__ qkvh,
                                                const float* __restrict__ gate,
                                                float* __restrict__ cbuf) {
    const int c = blockIdx.x, bh = blockIdx.y;
    const int b = bh / Hc, h = bh % Hc;
    const int tid = threadIdx.x;
    const int lane = tid & 63, w = tid >> 6;
    const int l15 = lane & 15, l4 = lane >> 4;

    __shared__ _Float16 Kt[64][72];   // [d][j]
    __shared__ _Float16 Vt[64][72];   // [e][j]
    __shared__ float ks[4][64];

    const size_t row0  = (size_t)b * Lc + c * CS;
    const size_t qbase = row0 * NQKV + h * DHc;
    const size_t gbase = row0 * Dc + h * DHc;

#pragma unroll
    for (int jj = 0; jj < 2; ++jj) {
        const int fi = tid + jj * 256;
        const int r = fi >> 3, c8 = (fi & 7) * 8;   // r = seq pos j
        const f16x8 k8 = *(const f16x8*)&qkvh[qbase + (size_t)r * NQKV + Dc + c8];
        const float4 g0 = *(const float4*)&gate[gbase + (size_t)r * Dc + c8];
        const float4 g1 = *(const float4*)&gate[gbase + (size_t)r * Dc + c8 + 4];
        const float gg[8] = {g0.x, g0.y, g0.z, g0.w, g1.x, g1.y, g1.z, g1.w};
        const f16x8 v8 = *(const f16x8*)&qkvh[qbase + (size_t)r * NQKV + 2 * Dc + c8];
#pragma unroll
        for (int i = 0; i < 8; ++i) {
            const float t = (float)k8[i] * gg[i];
            Kt[c8 + i][r] = (_Float16)(t > 0.f ? t + 1.f : expf(t));
            Vt[c8 + i][r] = v8[i];
        }
    }
    __syncthreads();

    // ksum partial: wave w sums j in [w*16, w*16+16), lane = d
    float s = 0.f;
#pragma unroll
    for (int j = 0; j < 16; ++j) s += (float)Kt[lane][w * 16 + j];
    ks[w][lane] = s;

    // MFMA: wave w computes S_T rows e = w*16..+16, all 64 d
    f32x4 acc[4];
    const f32x4 zero = {0.f, 0.f, 0.f, 0.f};
#pragma unroll
    for (int f = 0; f < 4; ++f) acc[f] = zero;
#pragma unroll
    for (int kb = 0; kb < 2; ++kb) {
        const f16x8 a = *(const f16x8*)&Vt[w * 16 + l15][kb * 32 + l4 * 8];
#pragma unroll
        for (int f = 0; f < 4; ++f) {
            const f16x8 bb = *(const f16x8*)&Kt[f * 16 + l15][kb * 32 + l4 * 8];
            acc[f] = __builtin_amdgcn_mfma_f32_16x16x32_f16(a, bb, acc[f], 0, 0, 0);
        }
    }
    float* out = cbuf + ((size_t)bh * NC + c) * STATE;
#pragma unroll
    for (int f = 0; f < 4; ++f) {
#pragma unroll
        for (int j = 0; j < 4; ++j) {
            const int e = w * 16 + l4 * 4 + j;
            out[e * DHc + f * 16 + l15] = acc[f][j];
        }
    }
    __syncthreads();
    if (tid < 64) out[DHc * DHc + tid] = ks[0][tid] + ks[1][tid] + ks[2][tid] + ks[3][tid];
}

// ---------------------------------------------------------------------------
// Phase B: exclusive prefix scan; fp32 accumulate, emit f16 pbuf only.
// ---------------------------------------------------------------------------
__global__ __launch_bounds__(256) void scan_kernel(const float* __restrict__ cbuf,
                                                   _Float16* __restrict__ pbuf) {
    const int idx = blockIdx.x * 256 + threadIdx.x;
    if (idx >= STATE) return;
    const float* base = cbuf + (size_t)blockIdx.y * NC * STATE + idx;
    _Float16* ob = pbuf + (size_t)blockIdx.y * NC * STATE + idx;
    float r = 0.f;
    for (int c = 0; c < NC; ++c) {
        ob[(size_t)c * STATE] = (_Float16)r;
        r += base[(size_t)c * STATE];
    }
}

// ---------------------------------------------------------------------------
// Phase C (MFMA): S = tril(Q@Kf^T); num = S@V + Q@P; den = rowsum + Q.kcP.
// Wave w owns output rows w*16..+16. 24 MFMAs/wave.
// ---------------------------------------------------------------------------
__global__ __launch_bounds__(256) void chunk_qkv_out(const _Float16* __restrict__ qkvh,
                                                     const float* __restrict__ gate,
                                                     const _Float16* __restrict__ pbuf,
                                                     _Float16* __restrict__ attnh) {
    const int c = blockIdx.x, bh = blockIdx.y;
    const int b = bh / Hc, h = bh % Hc;
    const int tid = threadIdx.x;
    const int lane = tid & 63, w = tid >> 6;
    const int l15 = lane & 15, l4 = lane >> 4;

    __shared__ _Float16 Qf[64][72];   // [l][d]
    __shared__ _Float16 Kf[64][72];   // [j][d]
    __shared__ _Float16 Vt[64][72];   // [e][j]
    __shared__ _Float16 Pt[64][72];   // [e][d]  (pbuf rows, already transposed)
    __shared__ _Float16 Sf[64][72];   // [l][j]
    __shared__ float dqs[64];
    __shared__ _Float16 kcs[64];

    const size_t row0  = (size_t)b * Lc + c * CS;
    const size_t qbase = row0 * NQKV + h * DHc;
    const size_t gbase = row0 * Dc + h * DHc;
    const _Float16* pb = pbuf + ((size_t)bh * NC + c) * STATE;

#pragma unroll
    for (int jj = 0; jj < 2; ++jj) {
        const int fi = tid + jj * 256;
        const int r = fi >> 3, c8 = (fi & 7) * 8;
        *(f16x8*)&Qf[r][c8] = *(const f16x8*)&qkvh[qbase + (size_t)r * NQKV + c8];
        const f16x8 k8 = *(const f16x8*)&qkvh[qbase + (size_t)r * NQKV + Dc + c8];
        const float4 g0 = *(const float4*)&gate[gbase + (size_t)r * Dc + c8];
        const float4 g1 = *(const float4*)&gate[gbase + (size_t)r * Dc + c8 + 4];
        const float gg[8] = {g0.x, g0.y, g0.z, g0.w, g1.x, g1.y, g1.z, g1.w};
        f16x8 kf;
#pragma unroll
        for (int i = 0; i < 8; ++i) {
            const float t = (float)k8[i] * gg[i];
            kf[i] = (_Float16)(t > 0.f ? t + 1.f : expf(t));
        }
        *(f16x8*)&Kf[r][c8] = kf;
        const f16x8 v8 = *(const f16x8*)&qkvh[qbase + (size_t)r * NQKV + 2 * Dc + c8];
#pragma unroll
        for (int i = 0; i < 8; ++i) Vt[c8 + i][r] = v8[i];
        *(f16x8*)&Pt[r][c8] = *(const f16x8*)&pb[r * 64 + c8];
    }
    if (tid < 64) kcs[tid] = pb[DHc * DHc + tid];
    __syncthreads();

    // Phase 1: S = Q @ Kf^T for rows w*16..+16
    f32x4 acc[4];
    const f32x4 zero = {0.f, 0.f, 0.f, 0.f};
#pragma unroll
    for (int f = 0; f < 4; ++f) acc[f] = zero;
#pragma unroll
    for (int kb = 0; kb < 2; ++kb) {
        const f16x8 a = *(const f16x8*)&Qf[w * 16 + l15][kb * 32 + l4 * 8];
#pragma unroll
        for (int f = 0; f < 4; ++f) {
            const f16x8 bb = *(const f16x8*)&Kf[f * 16 + l15][kb * 32 + l4 * 8];
            acc[f] = __builtin_amdgcn_mfma_f32_16x16x32_f16(a, bb, acc[f], 0, 0, 0);
        }
    }
    // mask (j <= l), rowsum, spill S to LDS f16
    float rs[4] = {0.f, 0.f, 0.f, 0.f};
#pragma unroll
    for (int f = 0; f < 4; ++f) {
#pragma unroll
        for (int j = 0; j < 4; ++j) {
            const int lrow = w * 16 + l4 * 4 + j;
            const int jcol = f * 16 + l15;
            const float m = (jcol <= lrow) ? acc[f][j] : 0.f;
            rs[j] += m;
            Sf[lrow][jcol] = (_Float16)m;
        }
    }
#pragma unroll
    for (int j = 0; j < 4; ++j) {
        rs[j] += __shfl_xor(rs[j], 1, 64);
        rs[j] += __shfl_xor(rs[j], 2, 64);
        rs[j] += __shfl_xor(rs[j], 4, 64);
        rs[j] += __shfl_xor(rs[j], 8, 64);
    }
    // dq[l] = Q[l] . kcP  (4 lanes per row)
    {
        const int rw = w * 16 + (lane >> 2);
        const int d0 = (lane & 3) * 16;
        float s = 0.f;
#pragma unroll
        for (int i = 0; i < 16; ++i) s += (float)Qf[rw][d0 + i] * (float)kcs[d0 + i];
        s += __shfl_xor(s, 1, 64);
        s += __shfl_xor(s, 2, 64);
        if ((lane & 3) == 0) dqs[rw] = s;
    }
    // Phase 2: num = Sf @ V + Qf @ P
    f32x4 num[4];
#pragma unroll
    for (int f = 0; f < 4; ++f) num[f] = zero;
#pragma unroll
    for (int kb = 0; kb < 2; ++kb) {
        const f16x8 a1 = *(const f16x8*)&Sf[w * 16 + l15][kb * 32 + l4 * 8];
        const f16x8 a2 = *(const f16x8*)&Qf[w * 16 + l15][kb * 32 + l4 * 8];
#pragma unroll
        for (int f = 0; f < 4; ++f) {
            const f16x8 bv = *(const f16x8*)&Vt[f * 16 + l15][kb * 32 + l4 * 8];
            num[f] = __builtin_amdgcn_mfma_f32_16x16x32_f16(a1, bv, num[f], 0, 0, 0);
            const f16x8 bp = *(const f16x8*)&Pt[f * 16 + l15][kb * 32 + l4 * 8];
            num[f] = __builtin_amdgcn_mfma_f32_16x16x32_f16(a2, bp, num[f], 0, 0, 0);
        }
    }
    // attn = num / (rowsum + dq + 1e-6), f16 out
#pragma unroll
    for (int f = 0; f < 4; ++f) {
#pragma unroll
        for (int j = 0; j < 4; ++j) {
            const int lrow = w * 16 + l4 * 4 + j;
            const int e = f * 16 + l15;
            const float dd = rs[j] + dqs[lrow] + 1e-6f;
            attnh[(row0 + lrow) * Dc + h * DHc + e] = (_Float16)(num[f][j] / dd);
        }
    }
}

// ---------------------------------------------------------------------------
// proj GEMM (unchanged from round 11 — passed)
// ---------------------------------------------------------------------------
__global__ __launch_bounds__(256) void gemm_proj(const _Float16* __restrict__ A,
                                                 const _Float16* __restrict__ B,
                                                 const float* __restrict__ bias,
                                                 float* __restrict__ C) {
    __shared__ _Float16 Alds[2][64 * 64];
    __shared__ _Float16 Blds[2][64 * 64];
    const int tid  = threadIdx.x;
    const int lane = tid & 63;
    const int wv  = tid >> 6;
    const int wr  = (wv >> 1) * 32;
    const int wc  = (wv & 1) * 32;
    const int l15 = lane & 15;
    const int l4  = lane >> 4;
    const int r8  = lane >> 3;
    const int ch  = lane & 7;
    const int sChunk = ((ch ^ r8) * 8);
    const int row0 = blockIdx.y * 64;
    const int col0 = blockIdx.x * 64;

    f32x4 acc[2][2];
    const f32x4 zero = {0.f, 0.f, 0.f, 0.f};
#pragma unroll
    for (int i = 0; i < 2; ++i)
#pragma unroll
        for (int j = 0; j < 2; ++j) acc[i][j] = zero;

    auto STAGE = [&](int buf, int s) {
        const _Float16* as = A + (size_t)(row0 + 16 * wv + r8) * 768 + s * 64 + sChunk;
        gll16(as,           &Alds[buf][(16 * wv) * 64]);
        gll16(as + 8 * 768, &Alds[buf][(16 * wv + 8) * 64]);
        const _Float16* bs = B + (size_t)(col0 + 16 * wv + r8) * 768 + s * 64 + sChunk;
        gll16(bs,           &Blds[buf][(16 * wv) * 64]);
        gll16(bs + 8 * 768, &Blds[buf][(16 * wv + 8) * 64]);
    };

    STAGE(0, 0);
    asm volatile("s_waitcnt vmcnt(0)" ::: "memory");
    __builtin_amdgcn_s_barrier();

    const int pa0 = ((l4)     ^ (l15 & 7)) * 8;
    const int pa1 = ((4 + l4) ^ (l15 & 7)) * 8;
    int buf = 0;
    for (int s = 0; s < 12; ++s) {
        if (s + 1 < 12) STAGE(buf ^ 1, s + 1);
        const _Float16* AB = Alds[buf];
        const _Float16* BB = Blds[buf];
        const f16x8 a00 = *(const f16x8*)&AB[(wr + l15) * 64 + pa0];
        const f16x8 a10 = *(const f16x8*)&AB[(wr + 16 + l15) * 64 + pa0];
        const f16x8 b00 = *(const f16x8*)&BB[(wc + l15) * 64 + pa0];
        const f16x8 b10 = *(const f16x8*)&BB[(wc + 16 + l15) * 64 + pa0];
        const f16x8 a01 = *(const f16x8*)&AB[(wr + l15) * 64 + pa1];
        const f16x8 a11 = *(const f16x8*)&AB[(wr + 16 + l15) * 64 + pa1];
        const f16x8 b01 = *(const f16x8*)&BB[(wc + l15) * 64 + pa1];
        const f16x8 b11 = *(const f16x8*)&BB[(wc + 16 + l15) * 64 + pa1];
        acc[0][0] = __builtin_amdgcn_mfma_f32_16x16x32_f16(a00, b00, acc[0][0], 0, 0, 0);
        acc[0][1] = __builtin_amdgcn_mfma_f32_16x16x32_f16(a00, b10, acc[0][1], 0, 0, 0);
        acc[1][0] = __builtin_amdgcn_mfma_f32_16x16x32_f16(a10, b00, acc[1][0], 0, 0, 0);
        acc[1][1] = __builtin_amdgcn_mfma_f32_16x16x32_f16(a10, b10, acc[1][1], 0, 0, 0);
        acc[0][0] = __builtin_amdgcn_mfma_f32_16x16x32_f16(a01, b01, acc[0][0], 0, 0, 0);
        acc[0][1] = __builtin_amdgcn_mfma_f32_16x16x32_f16(a01, b11, acc[0][1], 0, 0, 0);
        acc[1][0] = __builtin_amdgcn_mfma_f32_16x16x32_f16(a11, b01, acc[1][0], 0, 0, 0);
        acc[1][1] = __builtin_amdgcn_mfma_f32_16x16x32_f16(a11, b11, acc[1][1], 0, 0, 0);
        asm volatile("s_waitcnt vmcnt(0)" ::: "memory");
        __builtin_amdgcn_s_barrier();
        buf ^= 1;
    }

#pragma unroll
    for (int fi = 0; fi < 2; ++fi) {
#pragma unroll
        for (int fj = 0; fj < 2; ++fj) {
            const int col  = col0 + wc + fj * 16 + l15;
            const int rowb = row0 + wr + fi * 16 + l4 * 4;
            const float bv = bias[col];
#pragma unroll
            for (int j = 0; j < 4; ++j)
                C[(size_t)(rowb + j) * Dc + col] = acc[fi][fj][j] + bv;
        }
    }
}

// ---------------------------------------------------------------------------
extern "C" void kernel_launch(void* const* d_in, const int* in_sizes, int n_in,
                              void* d_out, int out_size, void* d_ws, size_t ws_size,
                              hipStream_t stream) {
    const float* x      = (const float*)d_in[0];
    const float* W_qkv  = (const float*)d_in[1];
    const float* b_qkv  = (const float*)d_in[2];
    const float* W_gate = (const float*)d_in[3];
    const float* b_gate = (const float*)d_in[4];
    const float* W_proj = (const float*)d_in[5];
    const float* b_proj = (const float*)d_in[6];
    const float* ln_g   = (const float*)d_in[7];
    const float* ln_b   = (const float*)d_in[8];

    float* out_proj = (float*)d_out;           // (B,L,D)
    float* out_gate = out_proj + (size_t)BLD;  // (B,L,D)

    _Float16* qkvh = (_Float16*)d_ws;                 // 3*BLD
    _Float16* xh   = qkvh + (size_t)3 * BLD;          // BLD
    _Float16* xnh  = xh + (size_t)BLD;                // BLD
    _Float16* wAll = xnh + (size_t)BLD;               // 3072*768
    _Float16* wph  = wAll + (size_t)NALL * Dc;        // 768*768
    float* cbuf    = (float*)(wph + (size_t)Dc * Dc); // 384*STATE fp32
    _Float16* pbuf = (_Float16*)(cbuf + (size_t)Bc * Hc * NC * STATE); // 384*STATE f16
    _Float16* attnh = wAll;                           // alias: wAll dead after gemm_gq

    // 1) prep: weight transposes + LayerNorm (one launch)
    prep_kernel<<<2880 + Mrows, 256, 0, stream>>>(W_gate, W_qkv, W_proj, x,
                                                  ln_g, ln_b, wAll, wph, xh, xnh);
    // 2) merged gate|qkv GEMM
    gemm_gq<<<dim3(NALL / 64, Mrows / 64), 256, 0, stream>>>(
        xh, xnh, wAll, b_gate, b_qkv, out_gate, qkvh);
    // 3-5) chunked causal linear attention (MFMA)
    chunk_kv<<<dim3(NC, Bc * Hc), 256, 0, stream>>>(qkvh, out_gate, cbuf);
    scan_kernel<<<dim3(17, Bc * Hc), 256, 0, stream>>>(cbuf, pbuf);
    chunk_qkv_out<<<dim3(NC, Bc * Hc), 256, 0, stream>>>(qkvh, out_gate, pbuf, attnh);
    // 6) out = attn @ W_proj + b_proj
    gemm_proj<<<dim3(Dc / 64, Mrows / 64), 256, 0, stream>>>(
        attnh, wph, b_proj, out_proj);
}